// Round 5
// baseline (1691.607 us; speedup 1.0000x reference)
//
#include <hip/hip_runtime.h>
#include <hip/hip_bf16.h>

typedef __hip_bfloat16 bf16;

#define BB 32
#define NN 128
#define FF 9
#define EE 8
#define HH 128
#define HD 256
#define NHEAD 4
#define DHEAD 64

__device__ __forceinline__ float us2f(unsigned short u) {
    return __uint_as_float(((unsigned int)u) << 16);
}
__device__ __forceinline__ unsigned short f2us_rne(float f) {
    unsigned int x = __float_as_uint(f);
    unsigned int r = (x + 0x7FFF + ((x >> 16) & 1)) >> 16;   // round-to-nearest-even
    return (unsigned short)r;
}

// Harness-expected symbol name (insurance; not used for real work).
__global__ void TransformerConvNet_85315230367963_kernel() {}

// Diagnostic sentinel: fill d_out (f32) with a distinctive value.
__global__ void k_sent(float* out, float val) {
    out[blockIdx.x * 256 + threadIdx.x] = val;   // 8192 total
}

// zero-fill
__global__ void k_zero(float* p) {
    p[blockIdx.x * 256 + threadIdx.x] = 0.f;
}

// ---------------- K1: adjv = adj * mask, mask = (0<adj<1) ----------------
__global__ void k_adjv(const float* adj, float* adjv) {
    int i = blockIdx.x * 256 + threadIdx.x;   // 524288 total
    float a = adj[i];
    adjv[i] = (a > 0.f && a < 1.0f) ? a : 0.f;
}

// ---------------- K2: base[bs][c] = src(bs) @ W1[:17] + b1 ----------------
__global__ void k_base(const float* nf, const int* et, const float* emb,
                       const float* W1, const float* b1, float* base) {
    int bs = blockIdx.x;        // 0..4095
    int c = threadIdx.x;        // 0..127
    int ty = et[bs];
    float acc = b1[c];
    for (int f = 0; f < FF; f++)
        acc += nf[bs * FF + f] * W1[f * HH + c];
    for (int e = 0; e < EE; e++)
        acc += emb[ty * EE + e] * W1[(FF + e) * HH + c];
    base[bs * HH + c] = acc;
}

// ---------------- K3: embed conv main loop ----------------
// block: 128 threads, (b, t-tile of 16, s-slice of 32). LDS ~49.3 KB.
#define TT 16
#define SQ 32

__global__ void k_econv(const float* adjv, const float* base, const float* W1,
                        const float* g1, const float* be1,
                        const float* Wh, const float* bh,
                        const float* gh, const float* beh,
                        float* x0) {
    __shared__ unsigned short WhL[HH * HH];   // 32 KB bf16 copy of Wh
    __shared__ float h1L[TT][132];            // 8.45 KB
    __shared__ float h2L[TT][132];            // 8.45 KB
    __shared__ float m1L[TT], r1L[TT], m2L[TT], r2L[TT];

    int blk = blockIdx.x;          // 1024 = 32 b * 8 ttile * 4 sslice
    int b  = blk >> 5;
    int tt = (blk >> 2) & 7;
    int sq = blk & 3;
    int t0 = tt * TT;
    int s0 = sq * SQ;
    int c = threadIdx.x;
    int tj = c >> 3;               // 0..15  (LN stats row)
    int l  = c & 7;                // 0..7

    // stage Wh (f32 global -> bf16 LDS), coalesced float4 reads
    for (int i = c * 4; i < HH * HH; i += 128 * 4) {
        float4 wv = *(const float4*)&Wh[i];
        WhL[i + 0] = f2us_rne(wv.x);
        WhL[i + 1] = f2us_rne(wv.y);
        WhL[i + 2] = f2us_rne(wv.z);
        WhL[i + 3] = f2us_rne(wv.w);
    }

    float w17  = W1[(FF + EE) * HH + c];
    float g1c  = g1[c],  be1c = be1[c];
    float bhc  = bh[c];
    float ghc  = gh[c],  behc = beh[c];

    float xacc[TT];
    for (int j = 0; j < TT; j++) xacc[j] = 0.f;

    __syncthreads();

    for (int s = s0; s < s0 + SQ; ++s) {
        float basec = base[(b * NN + s) * HH + c];
        const float* arow = adjv + (b * NN + s) * NN + t0;
        float av[TT];
        for (int j = 0; j < TT; j++) av[j] = arow[j];

        // h1 raw = relu(base + adjv*W1[17])
        for (int j = 0; j < TT; j++)
            h1L[j][c] = fmaxf(basec + av[j] * w17, 0.f);
        __syncthreads();
        {   // LN1 stats: 8 lanes per row
            float sm = 0.f, s2 = 0.f;
            for (int i = 0; i < 16; i++) {
                float vv = h1L[tj][l * 16 + i];
                sm += vv; s2 += vv * vv;
            }
            for (int m = 1; m < 8; m <<= 1) {
                sm += __shfl_xor(sm, m);
                s2 += __shfl_xor(s2, m);
            }
            if (l == 0) {
                float mn = sm * (1.f / 128.f);
                float var = s2 * (1.f / 128.f) - mn * mn;
                m1L[tj] = mn;
                r1L[tj] = rsqrtf(var + 1e-5f);
            }
        }
        __syncthreads();
        for (int j = 0; j < TT; j++)
            h1L[j][c] = (h1L[j][c] - m1L[j]) * r1L[j] * g1c + be1c;
        __syncthreads();

        // h2pre[t][c] = h1n[t][:] @ Wh[:,c] + bh[c]
        float hacc[TT];
        for (int j = 0; j < TT; j++) hacc[j] = bhc;
        for (int k = 0; k < HH; k += 4) {
            float w0 = us2f(WhL[(k + 0) * HH + c]);
            float w1 = us2f(WhL[(k + 1) * HH + c]);
            float w2 = us2f(WhL[(k + 2) * HH + c]);
            float w3 = us2f(WhL[(k + 3) * HH + c]);
            for (int j = 0; j < TT; j++) {
                hacc[j] += h1L[j][k + 0] * w0 + h1L[j][k + 1] * w1
                         + h1L[j][k + 2] * w2 + h1L[j][k + 3] * w3;
            }
        }
        for (int j = 0; j < TT; j++) {
            hacc[j] = fmaxf(hacc[j], 0.f);
            h2L[j][c] = hacc[j];
        }
        __syncthreads();
        {   // LN2 stats
            float sm = 0.f, s2 = 0.f;
            for (int i = 0; i < 16; i++) {
                float vv = h2L[tj][l * 16 + i];
                sm += vv; s2 += vv * vv;
            }
            for (int m = 1; m < 8; m <<= 1) {
                sm += __shfl_xor(sm, m);
                s2 += __shfl_xor(s2, m);
            }
            if (l == 0) {
                float mn = sm * (1.f / 128.f);
                float var = s2 * (1.f / 128.f) - mn * mn;
                m2L[tj] = mn;
                r2L[tj] = rsqrtf(var + 1e-5f);
            }
        }
        __syncthreads();
        for (int j = 0; j < TT; j++) {
            float h2n = (hacc[j] - m2L[j]) * r2L[j] * ghc + behc;
            xacc[j] += (av[j] != 0.f) ? h2n : 0.f;
        }
    }
    for (int j = 0; j < TT; j++)
        atomicAdd(&x0[(b * NN + (t0 + j)) * HH + c], xacc[j]);
}

// ---------------- K5: q,k,v,skip = x @ {Wq,Wk,Wv,Ws} + bias (IN runtime) ----
__global__ void k_qkvs(const float* x, int IN,
                       const float* Wq, const float* bq,
                       const float* Wk, const float* bk,
                       const float* Wv, const float* bv,
                       const float* Ws, const float* bs,
                       float* q, float* k, float* v, float* skip) {
    __shared__ float xL[8][260];        // 8.3 KB (IN <= 256)
    int r0 = blockIdx.x * 8;            // 512 blocks
    int c = threadIdx.x;                // 0..255
    for (int i = c; i < 8 * IN; i += 256)
        xL[i / IN][i % IN] = x[r0 * IN + i];
    __syncthreads();
    const float* Wm[4] = {Wq, Wk, Wv, Ws};
    const float* bm[4] = {bq, bk, bv, bs};
    float* om[4] = {q, k, v, skip};
    for (int m = 0; m < 4; m++) {
        const float* W = Wm[m];
        float bc = bm[m][c];
        float acc[8];
        for (int r = 0; r < 8; r++) acc[r] = bc;
        for (int kk = 0; kk < IN; kk += 4) {
            float w0 = W[(kk + 0) * HD + c];
            float w1 = W[(kk + 1) * HD + c];
            float w2 = W[(kk + 2) * HD + c];
            float w3 = W[(kk + 3) * HD + c];
            for (int r = 0; r < 8; r++) {
                acc[r] += xL[r][kk + 0] * w0 + xL[r][kk + 1] * w1
                        + xL[r][kk + 2] * w2 + xL[r][kk + 3] * w3;
            }
        }
        for (int r = 0; r < 8; r++) om[m][(r0 + r) * HD + c] = acc[r];
    }
}

// ---------------- K6: attention per (b, head, t-tile of 16) ----------------
// LDS: qL 4.16K + kvL 16.9K + lg 8.45K + ajT 8.45K + misc ~0.6K ~= 38.6 KB
__global__ void k_attn(const float* qb, const float* kb, const float* vb,
                       const float* adjv, const float* We, float* attn) {
    __shared__ float qL[16][65];
    __shared__ float kvL[64][66];     // K half in phase 1, V half in phase 2
    __shared__ float lg[16][132];     // logits, then alpha
    __shared__ float ajT[16][132];    // adjv^T
    __shared__ float weL[DHEAD];
    __shared__ float qeL[16];
    __shared__ float bL[16];

    int blk = blockIdx.x;          // 1024 = 32 b * 4 h * 8 ttile
    int b  = blk >> 5;
    int h  = (blk >> 3) & 3;
    int tt = blk & 7;
    int t0 = tt * 16;
    int tid = threadIdx.x;         // 0..255
    int w = tid >> 6;              // wave 0..3 owns t rows [w*4, w*4+4)
    int lane = tid & 63;

    for (int i = tid; i < 16 * 64; i += 256) {
        int t = i >> 6, d = i & 63;
        qL[t][d] = qb[(b * NN + t0 + t) * HD + h * DHEAD + d];
    }
    for (int i = tid; i < 16 * 128; i += 256) {
        int t = i >> 7, s = i & 127;
        ajT[t][s] = adjv[(b * NN + s) * NN + t0 + t];
    }
    if (tid < DHEAD) weL[tid] = We[h * DHEAD + tid];
    __syncthreads();
    if (tid < 16) {
        float z = 0.f;
        for (int d = 0; d < DHEAD; d++) z += qL[tid][d] * weL[d];
        qeL[tid] = z;
    }
    __syncthreads();

    // ---- logits in two s-halves ----
    for (int sh = 0; sh < 2; sh++) {
        for (int i = tid; i < 64 * 64; i += 256) {
            int s = i >> 6, d = i & 63;
            kvL[s][d] = kb[(b * NN + sh * 64 + s) * HD + h * DHEAD + d];
        }
        __syncthreads();
        for (int i = 0; i < 4; i++) {
            int t = w * 4 + i;
            float lacc = 0.f;
            for (int d = 0; d < DHEAD; d++)
                lacc += kvL[lane][d] * qL[t][d];
            float a = ajT[t][sh * 64 + lane];
            lacc = (lacc + a * qeL[t]) * 0.125f;
            lg[t][sh * 64 + lane] = (a != 0.f) ? lacc : -1e30f;
        }
        __syncthreads();
    }

    // ---- softmax per t row (wave-private rows, own-lane cols) ----
    for (int i = 0; i < 4; i++) {
        int t = w * 4 + i;
        float ml1 = lg[t][lane], ml2 = lg[t][lane + 64];
        float a1 = ajT[t][lane], a2 = ajT[t][lane + 64];
        float mx = fmaxf(ml1, ml2);
        for (int m = 1; m < 64; m <<= 1) mx = fmaxf(mx, __shfl_xor(mx, m));
        float e1 = (a1 != 0.f) ? __expf(ml1 - mx) : 0.f;
        float e2 = (a2 != 0.f) ? __expf(ml2 - mx) : 0.f;
        float sm = e1 + e2;
        for (int m = 1; m < 64; m <<= 1) sm += __shfl_xor(sm, m);
        float den = fmaxf(sm, 1e-16f);
        float al1 = e1 / den, al2 = e2 / den;
        float beta = al1 * a1 + al2 * a2;
        for (int m = 1; m < 64; m <<= 1) beta += __shfl_xor(beta, m);
        lg[t][lane] = al1;
        lg[t][lane + 64] = al2;
        if (lane == 0) bL[t] = beta;
    }
    __syncthreads();

    // ---- PV in two s-halves; lane = d ----
    float acc[4];
    for (int i = 0; i < 4; i++) acc[i] = bL[w * 4 + i] * weL[lane];
    for (int sh = 0; sh < 2; sh++) {
        for (int i = tid; i < 64 * 64; i += 256) {
            int s = i >> 6, d = i & 63;
            kvL[s][d] = vb[(b * NN + sh * 64 + s) * HD + h * DHEAD + d];
        }
        __syncthreads();
        for (int s = 0; s < 64; s++) {
            float vv = kvL[s][lane];
            for (int i = 0; i < 4; i++)
                acc[i] += lg[w * 4 + i][sh * 64 + s] * vv;
        }
        __syncthreads();
    }
    for (int i = 0; i < 4; i++)
        attn[(b * NN + t0 + w * 4 + i) * HD + h * DHEAD + lane] = acc[i];
}

// ---------------- K7: x = relu(attn + skip) ----------------
__global__ void k_resrelu(const float* a, const float* c, float* o) {
    int i = blockIdx.x * 256 + threadIdx.x;   // 1048576
    o[i] = fmaxf(a[i] + c[i], 0.f);
}

// ---------------- K8: gather agent rows -> f32 out ----------------
__global__ void k_gather(const float* x2, const int* agent, float* out) {
    int b = blockIdx.x;      // 32
    int c = threadIdx.x;     // 256
    out[b * HD + c] = x2[(b * NN + agent[b]) * HD + c];
}

// ---------------- launch ----------------
extern "C" void kernel_launch(void* const* d_in, const int* in_sizes, int n_in,
                              void* d_out, int out_size, void* d_ws, size_t ws_size,
                              hipStream_t stream) {
    float* out = (float*)d_out;

    (void)hipGetLastError();   // clear stale error
    // Stage-0 signal: if NO kernel ever runs, memset pattern (~12.08) shows
    // as absmax ~= 33 (ref in [0,45]) instead of 45.0.
    hipMemsetAsync(d_out, 0x41, (size_t)out_size * sizeof(float), stream);
    // If kernels run but pipeline dies mid-way: ~1042 signature.
    k_sent<<<32, 256, 0, stream>>>(out, -997.f);

    bool ok = (n_in == 31) && in_sizes[0] == BB * NN * FF && in_sizes[2] == BB * NN * NN
              && in_sizes[5] == (FF + EE + 1) * HH && in_sizes[13] == HH * HD
              && in_sizes[22] == HD * HD && out_size == BB * HD;
    if (!ok) { k_sent<<<32, 256, 0, stream>>>(out, -30000.f); return; }

    const size_t WS_NEED = (size_t)8912896 * 4;   // 35.7 MB
    if (ws_size < WS_NEED) { k_sent<<<32, 256, 0, stream>>>(out, -20000.f); return; }

    const float* nf    = (const float*)d_in[0];
    const int*   et    = (const int*)d_in[1];
    const float* adj   = (const float*)d_in[2];
    const int*   agent = (const int*)d_in[3];
    const float* emb   = (const float*)d_in[4];
    const float* W1    = (const float*)d_in[5];
    const float* b1    = (const float*)d_in[6];
    const float* g1    = (const float*)d_in[7];
    const float* be1   = (const float*)d_in[8];
    const float* Wh    = (const float*)d_in[9];
    const float* bh    = (const float*)d_in[10];
    const float* gh    = (const float*)d_in[11];
    const float* beh   = (const float*)d_in[12];
    const float* Wq1   = (const float*)d_in[13];
    const float* bq1   = (const float*)d_in[14];
    const float* Wk1   = (const float*)d_in[15];
    const float* bk1   = (const float*)d_in[16];
    const float* Wv1   = (const float*)d_in[17];
    const float* bv1   = (const float*)d_in[18];
    const float* We1   = (const float*)d_in[19];
    const float* Ws1   = (const float*)d_in[20];
    const float* bs1   = (const float*)d_in[21];
    const float* Wq2   = (const float*)d_in[22];
    const float* bq2   = (const float*)d_in[23];
    const float* Wk2   = (const float*)d_in[24];
    const float* bk2   = (const float*)d_in[25];
    const float* Wv2   = (const float*)d_in[26];
    const float* bv2   = (const float*)d_in[27];
    const float* We2   = (const float*)d_in[28];
    const float* Ws2   = (const float*)d_in[29];
    const float* bs2   = (const float*)d_in[30];

    float* ws   = (float*)d_ws;
    float* adjv = ws;                              // 524288
    float* base = adjv + BB * NN * NN;             // 524288
    float* x0   = base + BB * NN * HH;             // 524288
    float* q    = x0 + BB * NN * HH;               // below: BB*NN*HD = 1048576 each
    float* k    = q + BB * NN * HD;
    float* v    = k + BB * NN * HD;
    float* skip = v + BB * NN * HD;
    float* attn = skip + BB * NN * HD;
    float* x1   = attn + BB * NN * HD;
    float* x2   = x1 + BB * NN * HD;

    int fail = 0;
    hipError_t e;
#define CHK(stage) do { e = hipGetLastError(); if (e != hipSuccess && fail == 0) fail = (stage); } while (0)
    CHK(99);

    k_adjv<<<BB * NN * NN / 256, 256, 0, stream>>>(adj, adjv);                       CHK(1);
    k_base<<<BB * NN, HH, 0, stream>>>(nf, et, emb, W1, b1, base);                   CHK(2);
    k_zero<<<BB * NN * HH / 256, 256, 0, stream>>>(x0);                              CHK(3);
    k_econv<<<1024, 128, 0, stream>>>(adjv, base, W1, g1, be1, Wh, bh, gh, beh, x0); CHK(4);

    k_qkvs<<<BB * NN / 8, 256, 0, stream>>>(x0, HH, Wq1, bq1, Wk1, bk1, Wv1, bv1,
                                            Ws1, bs1, q, k, v, skip);                CHK(5);
    k_attn<<<1024, 256, 0, stream>>>(q, k, v, adjv, We1, attn);                      CHK(6);
    k_resrelu<<<BB * NN * HD / 256, 256, 0, stream>>>(attn, skip, x1);               CHK(7);

    k_qkvs<<<BB * NN / 8, 256, 0, stream>>>(x1, HD, Wq2, bq2, Wk2, bk2, Wv2, bv2,
                                            Ws2, bs2, q, k, v, skip);                CHK(8);
    k_attn<<<1024, 256, 0, stream>>>(q, k, v, adjv, We2, attn);                      CHK(9);
    k_resrelu<<<BB * NN * HD / 256, 256, 0, stream>>>(attn, skip, x2);               CHK(10);

    k_gather<<<BB, HD, 0, stream>>>(x2, agent, out);                                 CHK(11);
#undef CHK

    if (fail != 0)
        k_sent<<<32, 256, 0, stream>>>(out, -(1000.f + 500.f * (float)fail));
}

// Round 7
// 809.612 us; speedup vs baseline: 2.0894x; 2.0894x over previous
//
#include <hip/hip_runtime.h>
#include <hip/hip_bf16.h>

typedef __hip_bfloat16 bf16;
typedef unsigned short ushort_t;
typedef __attribute__((ext_vector_type(8))) short short8;
typedef __attribute__((ext_vector_type(4))) float fx4;

#define BB 32
#define NN 128
#define FF 9
#define EE 8
#define HH 128
#define HD 256
#define NHEAD 4
#define DHEAD 64

__device__ __forceinline__ float us2f(ushort_t u) {
    return __uint_as_float(((unsigned int)u) << 16);
}
__device__ __forceinline__ ushort_t f2us_rne(float f) {
    unsigned int x = __float_as_uint(f);
    unsigned int r = (x + 0x7FFF + ((x >> 16) & 1)) >> 16;   // round-to-nearest-even
    return (ushort_t)r;
}

__global__ void TransformerConvNet_85315230367963_kernel() {}

// Diagnostic sentinel
__global__ void k_sent(float* out, float val) {
    out[blockIdx.x * 256 + threadIdx.x] = val;
}

__global__ void k_zero(float* p) {
    p[blockIdx.x * 256 + threadIdx.x] = 0.f;
}

// ---------------- K1: adjv = adj * mask, mask = (0<adj<1) ----------------
__global__ void k_adjv(const float* adj, float* adjv) {
    int i = blockIdx.x * 256 + threadIdx.x;
    float a = adj[i];
    adjv[i] = (a > 0.f && a < 1.0f) ? a : 0.f;
}

// ---------------- K2: base[bs][c] = src(bs) @ W1[:17] + b1 ----------------
__global__ void k_base(const float* nf, const int* et, const float* emb,
                       const float* W1, const float* b1, float* base) {
    int bs = blockIdx.x;
    int c = threadIdx.x;
    int ty = et[bs];
    float acc = b1[c];
    for (int f = 0; f < FF; f++)
        acc += nf[bs * FF + f] * W1[f * HH + c];
    for (int e = 0; e < EE; e++)
        acc += emb[ty * EE + e] * W1[(FF + e) * HH + c];
    base[bs * HH + c] = acc;
}

// ---------------- K_prep: Wh' = g1*Wh split into bf16 hi/lo, swizzled ------
// Also W1s[n] = sum_k Wh'[k][n], cb[n] = sum_k be1[k]*Wh[k][n] + bh[n].
// Swizzle: element (n,k) stored at n*128 + (k ^ (8*(n&15))).
__global__ void k_prep(const float* Wh, const float* g1, const float* be1,
                       const float* bh, ushort_t* BhiG, ushort_t* BloG,
                       float* W1s, float* cbv) {
    int n = blockIdx.x;      // 0..127
    int t = threadIdx.x;     // 0..63
    int sw = 8 * (n & 15);
    float s1 = 0.f, s2 = 0.f;
    for (int kk = 0; kk < 2; kk++) {
        int k = t + kk * 64;
        float w = Wh[k * HH + n];
        float wp = g1[k] * w;
        ushort_t hb = f2us_rne(wp);
        float lo = wp - us2f(hb);
        BhiG[n * HH + (k ^ sw)] = hb;
        BloG[n * HH + (k ^ sw)] = f2us_rne(lo);
        s1 += wp;
        s2 += be1[k] * w;
    }
    for (int m = 1; m < 64; m <<= 1) {
        s1 += __shfl_xor(s1, m);
        s2 += __shfl_xor(s2, m);
    }
    if (t == 0) { W1s[n] = s1; cbv[n] = s2 + bh[n]; }
}

// ---------------- K3: embed conv, MFMA (split-bf16 ~= f32 precision) -------
// Grid 512 = 32 b * 8 ttile * 2 shalf. 256 thr (4 waves), each wave 16 s.
// LDS = 64 KB (Bhi+Blo). Zero barriers in the s-loop.
__global__ void __launch_bounds__(256) k_econv_mfma(
    const float* adjv, const float* base, const float* W1,
    const ushort_t* BhiG, const ushort_t* BloG,
    const float* W1s, const float* cbv,
    const float* ghp, const float* behp, float* x0)
{
    __shared__ __align__(16) ushort_t Bhi[HH * HH];   // 32 KB
    __shared__ __align__(16) ushort_t Blo[HH * HH];   // 32 KB

    int blk = blockIdx.x;
    int b  = blk >> 4;
    int tt = (blk >> 1) & 7;
    int sh = blk & 1;
    int t0 = tt * 16;
    int tid = threadIdx.x;
    int wv  = tid >> 6;
    int lane = tid & 63;
    int nl = lane & 15;
    int quad = lane >> 4;

    // stage B (pre-swizzled in global) -> LDS, straight copy
    {
        const uint4* srcH = (const uint4*)BhiG;
        const uint4* srcL = (const uint4*)BloG;
        uint4* dstH = (uint4*)Bhi;
        uint4* dstL = (uint4*)Blo;
        for (int i = tid; i < HH * HH / 8; i += 256) {
            dstH[i] = srcH[i];
            dstL[i] = srcL[i];
        }
    }

    // per-lane s-invariant constants: c(tile) = tile*16 + nl
    float W1s_r[8], cb_r[8], gh_r[8], beh_r[8];
#pragma unroll
    for (int tile = 0; tile < 8; tile++) {
        int c = tile * 16 + nl;
        W1s_r[tile] = W1s[c];
        cb_r[tile]  = cbv[c];
        gh_r[tile]  = ghp[c];
        beh_r[tile] = behp[c];
    }
    // w17 slices: k = quad*8 + 32*st + j
    float w17v[4][8];
#pragma unroll
    for (int st = 0; st < 4; st++) {
        const float* p = W1 + 17 * HH + quad * 8 + 32 * st;
        float4 a = *(const float4*)p;
        float4 bq = *(const float4*)(p + 4);
        w17v[st][0] = a.x;  w17v[st][1] = a.y;  w17v[st][2] = a.z;  w17v[st][3] = a.w;
        w17v[st][4] = bq.x; w17v[st][5] = bq.y; w17v[st][6] = bq.z; w17v[st][7] = bq.w;
    }

    fx4 xacc[8];
#pragma unroll
    for (int tile = 0; tile < 8; tile++) xacc[tile] = (fx4){0.f, 0.f, 0.f, 0.f};

    __syncthreads();

    for (int i = 0; i < 16; i++) {
        int s = sh * 64 + wv * 16 + i;
        const float* brow = base + (b * NN + s) * HH;
        float avv = adjv[(b * NN + s) * NN + t0 + nl];

        // ---- build A = relu(base + avv*w17), split hi/lo; LN1 partial stats
        short8 Ahi[4], Alo[4];
        float sm = 0.f, s2 = 0.f;
#pragma unroll
        for (int st = 0; st < 4; st++) {
            const float* p = brow + quad * 8 + 32 * st;
            float4 b0 = *(const float4*)p;
            float4 b1q = *(const float4*)(p + 4);
            float h[8] = {b0.x, b0.y, b0.z, b0.w, b1q.x, b1q.y, b1q.z, b1q.w};
            short8 ah, al;
#pragma unroll
            for (int j = 0; j < 8; j++) {
                float v = fmaxf(h[j] + avv * w17v[st][j], 0.f);
                sm += v; s2 += v * v;
                ushort_t hb = f2us_rne(v);
                float lo = v - us2f(hb);
                ah[j] = (short)hb;
                al[j] = (short)f2us_rne(lo);
            }
            Ahi[st] = ah; Alo[st] = al;
        }
        sm += __shfl_xor(sm, 16); sm += __shfl_xor(sm, 32);
        s2 += __shfl_xor(s2, 16); s2 += __shfl_xor(s2, 32);
        float m1 = sm * (1.f / 128.f);
        float r1 = rsqrtf(s2 * (1.f / 128.f) - m1 * m1 + 1e-5f);

        // shuffle LN1 stats + mask values into D (row = quad*4+r) layout
        float m1d[4], r1d[4], avd[4];
#pragma unroll
        for (int r = 0; r < 4; r++) {
            int src = quad * 4 + r;
            m1d[r] = __shfl(m1, src);
            r1d[r] = __shfl(r1, src);
            avd[r] = __shfl(avv, src);
        }

        // ---- GEMM: G = h1raw @ Wh'  (3-mfma split product)
        fx4 G[8];
#pragma unroll
        for (int tile = 0; tile < 8; tile++) G[tile] = (fx4){0.f, 0.f, 0.f, 0.f};
#pragma unroll
        for (int st = 0; st < 4; st++) {
            int koff = quad * 8 + 32 * st;
#pragma unroll
            for (int tile = 0; tile < 8; tile++) {
                int n = tile * 16 + nl;
                int off = n * HH + (koff ^ (nl * 8));
                short8 bh8 = *(const short8*)(&Bhi[off]);
                short8 bl8 = *(const short8*)(&Blo[off]);
                G[tile] = __builtin_amdgcn_mfma_f32_16x16x32_bf16(Ahi[st], bh8, G[tile], 0, 0, 0);
                G[tile] = __builtin_amdgcn_mfma_f32_16x16x32_bf16(Alo[st], bh8, G[tile], 0, 0, 0);
                G[tile] = __builtin_amdgcn_mfma_f32_16x16x32_bf16(Ahi[st], bl8, G[tile], 0, 0, 0);
            }
        }

        // ---- post: h2 = relu(r1*(G - m1*W1s) + cb); LN2 over c; mask-acc
        float sm2[4] = {0.f, 0.f, 0.f, 0.f}, ss2[4] = {0.f, 0.f, 0.f, 0.f};
#pragma unroll
        for (int tile = 0; tile < 8; tile++) {
#pragma unroll
            for (int r = 0; r < 4; r++) {
                float h2 = fmaxf(r1d[r] * (G[tile][r] - m1d[r] * W1s_r[tile]) + cb_r[tile], 0.f);
                sm2[r] += h2; ss2[r] += h2 * h2;
            }
        }
#pragma unroll
        for (int r = 0; r < 4; r++) {
#pragma unroll
            for (int m = 1; m < 16; m <<= 1) {
                sm2[r] += __shfl_xor(sm2[r], m);
                ss2[r] += __shfl_xor(ss2[r], m);
            }
        }
        float mean2[4], r2v[4];
#pragma unroll
        for (int r = 0; r < 4; r++) {
            mean2[r] = sm2[r] * (1.f / 128.f);
            float var = ss2[r] * (1.f / 128.f) - mean2[r] * mean2[r];
            r2v[r] = rsqrtf(var + 1e-5f);
        }
#pragma unroll
        for (int tile = 0; tile < 8; tile++) {
#pragma unroll
            for (int r = 0; r < 4; r++) {
                float h2 = fmaxf(r1d[r] * (G[tile][r] - m1d[r] * W1s_r[tile]) + cb_r[tile], 0.f);
                float h2n = (h2 - mean2[r]) * r2v[r] * gh_r[tile] + beh_r[tile];
                if (avd[r] != 0.f) xacc[tile][r] += h2n;
            }
        }
    }

#pragma unroll
    for (int tile = 0; tile < 8; tile++)
#pragma unroll
        for (int r = 0; r < 4; r++)
            atomicAdd(&x0[(b * NN + t0 + quad * 4 + r) * HH + tile * 16 + nl], xacc[tile][r]);
}

// ---------------- K5: q,k,v,skip = x @ {Wq,Wk,Wv,Ws} + bias ----------------
__global__ void k_qkvs(const float* x, int IN,
                       const float* Wq, const float* bq,
                       const float* Wk, const float* bk,
                       const float* Wv, const float* bv,
                       const float* Ws, const float* bs,
                       float* q, float* k, float* v, float* skip) {
    __shared__ float xL[8][260];
    int r0 = blockIdx.x * 8;
    int c = threadIdx.x;
    for (int i = c; i < 8 * IN; i += 256)
        xL[i / IN][i % IN] = x[r0 * IN + i];
    __syncthreads();
    const float* Wm[4] = {Wq, Wk, Wv, Ws};
    const float* bm[4] = {bq, bk, bv, bs};
    float* om[4] = {q, k, v, skip};
    for (int m = 0; m < 4; m++) {
        const float* W = Wm[m];
        float bc = bm[m][c];
        float acc[8];
        for (int r = 0; r < 8; r++) acc[r] = bc;
        for (int kk = 0; kk < IN; kk += 4) {
            float w0 = W[(kk + 0) * HD + c];
            float w1 = W[(kk + 1) * HD + c];
            float w2 = W[(kk + 2) * HD + c];
            float w3 = W[(kk + 3) * HD + c];
            for (int r = 0; r < 8; r++) {
                acc[r] += xL[r][kk + 0] * w0 + xL[r][kk + 1] * w1
                        + xL[r][kk + 2] * w2 + xL[r][kk + 3] * w3;
            }
        }
        for (int r = 0; r < 8; r++) om[m][(r0 + r) * HD + c] = acc[r];
    }
}

// ---------------- K6: attention per (b, head, t-tile of 16) ----------------
__global__ void k_attn(const float* qb, const float* kb, const float* vb,
                       const float* adjv, const float* We, float* attn) {
    __shared__ float qL[16][65];
    __shared__ float kvL[64][66];
    __shared__ float lg[16][132];
    __shared__ float ajT[16][132];
    __shared__ float weL[DHEAD];
    __shared__ float qeL[16];
    __shared__ float bL[16];

    int blk = blockIdx.x;
    int b  = blk >> 5;
    int h  = (blk >> 3) & 3;
    int tt = blk & 7;
    int t0 = tt * 16;
    int tid = threadIdx.x;
    int w = tid >> 6;
    int lane = tid & 63;

    for (int i = tid; i < 16 * 64; i += 256) {
        int t = i >> 6, d = i & 63;
        qL[t][d] = qb[(b * NN + t0 + t) * HD + h * DHEAD + d];
    }
    for (int i = tid; i < 16 * 128; i += 256) {
        int t = i >> 7, s = i & 127;
        ajT[t][s] = adjv[(b * NN + s) * NN + t0 + t];
    }
    if (tid < DHEAD) weL[tid] = We[h * DHEAD + tid];
    __syncthreads();
    if (tid < 16) {
        float z = 0.f;
        for (int d = 0; d < DHEAD; d++) z += qL[tid][d] * weL[d];
        qeL[tid] = z;
    }
    __syncthreads();

    for (int sh = 0; sh < 2; sh++) {
        for (int i = tid; i < 64 * 64; i += 256) {
            int s = i >> 6, d = i & 63;
            kvL[s][d] = kb[(b * NN + sh * 64 + s) * HD + h * DHEAD + d];
        }
        __syncthreads();
        for (int i = 0; i < 4; i++) {
            int t = w * 4 + i;
            float lacc = 0.f;
            for (int d = 0; d < DHEAD; d++)
                lacc += kvL[lane][d] * qL[t][d];
            float a = ajT[t][sh * 64 + lane];
            lacc = (lacc + a * qeL[t]) * 0.125f;
            lg[t][sh * 64 + lane] = (a != 0.f) ? lacc : -1e30f;
        }
        __syncthreads();
    }

    for (int i = 0; i < 4; i++) {
        int t = w * 4 + i;
        float ml1 = lg[t][lane], ml2 = lg[t][lane + 64];
        float a1 = ajT[t][lane], a2 = ajT[t][lane + 64];
        float mx = fmaxf(ml1, ml2);
        for (int m = 1; m < 64; m <<= 1) mx = fmaxf(mx, __shfl_xor(mx, m));
        float e1 = (a1 != 0.f) ? __expf(ml1 - mx) : 0.f;
        float e2 = (a2 != 0.f) ? __expf(ml2 - mx) : 0.f;
        float smv = e1 + e2;
        for (int m = 1; m < 64; m <<= 1) smv += __shfl_xor(smv, m);
        float den = fmaxf(smv, 1e-16f);
        float al1 = e1 / den, al2 = e2 / den;
        float beta = al1 * a1 + al2 * a2;
        for (int m = 1; m < 64; m <<= 1) beta += __shfl_xor(beta, m);
        lg[t][lane] = al1;
        lg[t][lane + 64] = al2;
        if (lane == 0) bL[t] = beta;
    }
    __syncthreads();

    float acc[4];
    for (int i = 0; i < 4; i++) acc[i] = bL[w * 4 + i] * weL[lane];
    for (int sh = 0; sh < 2; sh++) {
        for (int i = tid; i < 64 * 64; i += 256) {
            int s = i >> 6, d = i & 63;
            kvL[s][d] = vb[(b * NN + sh * 64 + s) * HD + h * DHEAD + d];
        }
        __syncthreads();
        for (int s = 0; s < 64; s++) {
            float vv = kvL[s][lane];
            for (int i = 0; i < 4; i++)
                acc[i] += lg[w * 4 + i][sh * 64 + s] * vv;
        }
        __syncthreads();
    }
    for (int i = 0; i < 4; i++)
        attn[(b * NN + t0 + w * 4 + i) * HD + h * DHEAD + lane] = acc[i];
}

// ---------------- K7: x = relu(attn + skip) ----------------
__global__ void k_resrelu(const float* a, const float* c, float* o) {
    int i = blockIdx.x * 256 + threadIdx.x;
    o[i] = fmaxf(a[i] + c[i], 0.f);
}

// ---------------- K8: gather agent rows -> f32 out ----------------
__global__ void k_gather(const float* x2, const int* agent, float* out) {
    int b = blockIdx.x;
    int c = threadIdx.x;
    out[b * HD + c] = x2[(b * NN + agent[b]) * HD + c];
}

// ---------------- launch ----------------
extern "C" void kernel_launch(void* const* d_in, const int* in_sizes, int n_in,
                              void* d_out, int out_size, void* d_ws, size_t ws_size,
                              hipStream_t stream) {
    float* out = (float*)d_out;
    (void)hipGetLastError();

    bool ok = (n_in == 31) && in_sizes[0] == BB * NN * FF && in_sizes[2] == BB * NN * NN
              && in_sizes[5] == (FF + EE + 1) * HH && in_sizes[13] == HH * HD
              && in_sizes[22] == HD * HD && out_size == BB * HD;
    if (!ok) { k_sent<<<32, 256, 0, stream>>>(out, -30000.f); return; }

    const size_t WS_NEED = (size_t)8912896 * 4;
    if (ws_size < WS_NEED) { k_sent<<<32, 256, 0, stream>>>(out, -20000.f); return; }

    const float* nf    = (const float*)d_in[0];
    const int*   et    = (const int*)d_in[1];
    const float* adj   = (const float*)d_in[2];
    const int*   agent = (const int*)d_in[3];
    const float* emb   = (const float*)d_in[4];
    const float* W1    = (const float*)d_in[5];
    const float* b1    = (const float*)d_in[6];
    const float* g1    = (const float*)d_in[7];
    const float* be1   = (const float*)d_in[8];
    const float* Wh    = (const float*)d_in[9];
    const float* bh    = (const float*)d_in[10];
    const float* gh    = (const float*)d_in[11];
    const float* beh   = (const float*)d_in[12];
    const float* Wq1   = (const float*)d_in[13];
    const float* bq1   = (const float*)d_in[14];
    const float* Wk1   = (const float*)d_in[15];
    const float* bk1   = (const float*)d_in[16];
    const float* Wv1   = (const float*)d_in[17];
    const float* bv1   = (const float*)d_in[18];
    const float* We1   = (const float*)d_in[19];
    const float* Ws1   = (const float*)d_in[20];
    const float* bs1   = (const float*)d_in[21];
    const float* Wq2   = (const float*)d_in[22];
    const float* bq2   = (const float*)d_in[23];
    const float* Wk2   = (const float*)d_in[24];
    const float* bk2   = (const float*)d_in[25];
    const float* Wv2   = (const float*)d_in[26];
    const float* bv2   = (const float*)d_in[27];
    const float* We2   = (const float*)d_in[28];
    const float* Ws2   = (const float*)d_in[29];
    const float* bs2   = (const float*)d_in[30];

    float* ws   = (float*)d_ws;
    float* adjv = ws;                              // 524288
    float* base = adjv + BB * NN * NN;             // 524288
    float* x0   = base + BB * NN * HH;             // 524288
    float* q    = x0 + BB * NN * HH;               // BB*NN*HD each below
    float* k    = q + BB * NN * HD;
    float* v    = k + BB * NN * HD;
    float* skip = v + BB * NN * HD;
    float* attn = skip + BB * NN * HD;
    float* x1   = attn + BB * NN * HD;
    float* x2   = x1 + BB * NN * HD;

    // k_prep outputs live in the q region (first written AFTER econv).
    // BhiG: q floats [0,8192). BloG: [8192,16384). W1s/cb MUST be past 16384
    // (R6 bug: they were at 8192/8320, inside BloG -> garbage bf16 planes).
    ushort_t* BhiG = (ushort_t*)q;                 // 16384 ushorts = 8192 floats
    ushort_t* BloG = BhiG + HH * HH;               // next 8192 floats
    float*    W1sW = q + 16384;                    // 128 floats
    float*    cbW  = q + 16512;                    // 128 floats

    int fail = 0;
    hipError_t e;
#define CHK(stage) do { e = hipGetLastError(); if (e != hipSuccess && fail == 0) fail = (stage); } while (0)

    k_adjv<<<BB * NN * NN / 256, 256, 0, stream>>>(adj, adjv);                       CHK(1);
    k_base<<<BB * NN, HH, 0, stream>>>(nf, et, emb, W1, b1, base);                   CHK(2);
    k_zero<<<BB * NN * HH / 256, 256, 0, stream>>>(x0);                              CHK(3);
    k_prep<<<HH, 64, 0, stream>>>(Wh, g1, be1, bh, BhiG, BloG, W1sW, cbW);           CHK(4);
    k_econv_mfma<<<512, 256, 0, stream>>>(adjv, base, W1, BhiG, BloG, W1sW, cbW,
                                          gh, beh, x0);                              CHK(5);

    k_qkvs<<<BB * NN / 8, 256, 0, stream>>>(x0, HH, Wq1, bq1, Wk1, bk1, Wv1, bv1,
                                            Ws1, bs1, q, k, v, skip);                CHK(6);
    k_attn<<<1024, 256, 0, stream>>>(q, k, v, adjv, We1, attn);                      CHK(7);
    k_resrelu<<<BB * NN * HD / 256, 256, 0, stream>>>(attn, skip, x1);               CHK(8);

    k_qkvs<<<BB * NN / 8, 256, 0, stream>>>(x1, HD, Wq2, bq2, Wk2, bk2, Wv2, bv2,
                                            Ws2, bs2, q, k, v, skip);                CHK(9);
    k_attn<<<1024, 256, 0, stream>>>(q, k, v, adjv, We2, attn);                      CHK(10);
    k_resrelu<<<BB * NN * HD / 256, 256, 0, stream>>>(attn, skip, x2);               CHK(11);

    k_gather<<<BB, HD, 0, stream>>>(x2, agent, out);                                 CHK(12);
#undef CHK

    if (fail != 0)
        k_sent<<<32, 256, 0, stream>>>(out, -(1000.f + 500.f * (float)fail));
}

// Round 8
// 566.016 us; speedup vs baseline: 2.9886x; 1.4304x over previous
//
#include <hip/hip_runtime.h>
#include <hip/hip_bf16.h>

typedef __hip_bfloat16 bf16;
typedef unsigned short ushort_t;
typedef __attribute__((ext_vector_type(8))) short short8;
typedef __attribute__((ext_vector_type(4))) float fx4;

#define BB 32
#define NN 128
#define FF 9
#define EE 8
#define HH 128
#define HD 256
#define NHEAD 4
#define DHEAD 64

__device__ __forceinline__ float us2f(ushort_t u) {
    return __uint_as_float(((unsigned int)u) << 16);
}
__device__ __forceinline__ ushort_t f2us_rne(float f) {
    unsigned int x = __float_as_uint(f);
    unsigned int r = (x + 0x7FFF + ((x >> 16) & 1)) >> 16;   // round-to-nearest-even
    return (ushort_t)r;
}

__global__ void TransformerConvNet_85315230367963_kernel() {}

// Diagnostic sentinel
__global__ void k_sent(float* out, float val) {
    out[blockIdx.x * 256 + threadIdx.x] = val;
}

__global__ void k_zero(float* p) {
    p[blockIdx.x * 256 + threadIdx.x] = 0.f;
}

// ---------------- K1: adjv = adj * mask, mask = (0<adj<1) ----------------
__global__ void k_adjv(const float* adj, float* adjv) {
    int i = blockIdx.x * 256 + threadIdx.x;
    float a = adj[i];
    adjv[i] = (a > 0.f && a < 1.0f) ? a : 0.f;
}

// ---------------- K2: base[bs][c] = src(bs) @ W1[:17] + b1 ----------------
__global__ void k_base(const float* nf, const int* et, const float* emb,
                       const float* W1, const float* b1, float* base) {
    int bs = blockIdx.x;
    int c = threadIdx.x;
    int ty = et[bs];
    float acc = b1[c];
    for (int f = 0; f < FF; f++)
        acc += nf[bs * FF + f] * W1[f * HH + c];
    for (int e = 0; e < EE; e++)
        acc += emb[ty * EE + e] * W1[(FF + e) * HH + c];
    base[bs * HH + c] = acc;
}

// ---------------- K_prep: Wh' = g1*Wh split into bf16 hi/lo, swizzled ------
// Also W1s[n] = sum_k Wh'[k][n], cb[n] = sum_k be1[k]*Wh[k][n] + bh[n].
// Swizzle: element (n,k) stored at n*128 + (k ^ (8*(n&15))).
__global__ void k_prep(const float* Wh, const float* g1, const float* be1,
                       const float* bh, ushort_t* BhiG, ushort_t* BloG,
                       float* W1s, float* cbv) {
    int n = blockIdx.x;      // 0..127
    int t = threadIdx.x;     // 0..63
    int sw = 8 * (n & 15);
    float s1 = 0.f, s2 = 0.f;
    for (int kk = 0; kk < 2; kk++) {
        int k = t + kk * 64;
        float w = Wh[k * HH + n];
        float wp = g1[k] * w;
        ushort_t hb = f2us_rne(wp);
        float lo = wp - us2f(hb);
        BhiG[n * HH + (k ^ sw)] = hb;
        BloG[n * HH + (k ^ sw)] = f2us_rne(lo);
        s1 += wp;
        s2 += be1[k] * w;
    }
    for (int m = 1; m < 64; m <<= 1) {
        s1 += __shfl_xor(s1, m);
        s2 += __shfl_xor(s2, m);
    }
    if (t == 0) { W1s[n] = s1; cbv[n] = s2 + bh[n]; }
}

// ---------------- K3: embed conv, MFMA (split-bf16 ~= f32 precision) -------
__global__ void __launch_bounds__(256) k_econv_mfma(
    const float* adjv, const float* base, const float* W1,
    const ushort_t* BhiG, const ushort_t* BloG,
    const float* W1s, const float* cbv,
    const float* ghp, const float* behp, float* x0)
{
    __shared__ __align__(16) ushort_t Bhi[HH * HH];   // 32 KB
    __shared__ __align__(16) ushort_t Blo[HH * HH];   // 32 KB

    int blk = blockIdx.x;
    int b  = blk >> 4;
    int tt = (blk >> 1) & 7;
    int sh = blk & 1;
    int t0 = tt * 16;
    int tid = threadIdx.x;
    int wv  = tid >> 6;
    int lane = tid & 63;
    int nl = lane & 15;
    int quad = lane >> 4;

    {
        const uint4* srcH = (const uint4*)BhiG;
        const uint4* srcL = (const uint4*)BloG;
        uint4* dstH = (uint4*)Bhi;
        uint4* dstL = (uint4*)Blo;
        for (int i = tid; i < HH * HH / 8; i += 256) {
            dstH[i] = srcH[i];
            dstL[i] = srcL[i];
        }
    }

    float W1s_r[8], cb_r[8], gh_r[8], beh_r[8];
#pragma unroll
    for (int tile = 0; tile < 8; tile++) {
        int c = tile * 16 + nl;
        W1s_r[tile] = W1s[c];
        cb_r[tile]  = cbv[c];
        gh_r[tile]  = ghp[c];
        beh_r[tile] = behp[c];
    }
    float w17v[4][8];
#pragma unroll
    for (int st = 0; st < 4; st++) {
        const float* p = W1 + 17 * HH + quad * 8 + 32 * st;
        float4 a = *(const float4*)p;
        float4 bq = *(const float4*)(p + 4);
        w17v[st][0] = a.x;  w17v[st][1] = a.y;  w17v[st][2] = a.z;  w17v[st][3] = a.w;
        w17v[st][4] = bq.x; w17v[st][5] = bq.y; w17v[st][6] = bq.z; w17v[st][7] = bq.w;
    }

    fx4 xacc[8];
#pragma unroll
    for (int tile = 0; tile < 8; tile++) xacc[tile] = (fx4){0.f, 0.f, 0.f, 0.f};

    __syncthreads();

    for (int i = 0; i < 16; i++) {
        int s = sh * 64 + wv * 16 + i;
        const float* brow = base + (b * NN + s) * HH;
        float avv = adjv[(b * NN + s) * NN + t0 + nl];

        short8 Ahi[4], Alo[4];
        float sm = 0.f, s2 = 0.f;
#pragma unroll
        for (int st = 0; st < 4; st++) {
            const float* p = brow + quad * 8 + 32 * st;
            float4 b0 = *(const float4*)p;
            float4 b1q = *(const float4*)(p + 4);
            float h[8] = {b0.x, b0.y, b0.z, b0.w, b1q.x, b1q.y, b1q.z, b1q.w};
            short8 ah, al;
#pragma unroll
            for (int j = 0; j < 8; j++) {
                float v = fmaxf(h[j] + avv * w17v[st][j], 0.f);
                sm += v; s2 += v * v;
                ushort_t hb = f2us_rne(v);
                float lo = v - us2f(hb);
                ah[j] = (short)hb;
                al[j] = (short)f2us_rne(lo);
            }
            Ahi[st] = ah; Alo[st] = al;
        }
        sm += __shfl_xor(sm, 16); sm += __shfl_xor(sm, 32);
        s2 += __shfl_xor(s2, 16); s2 += __shfl_xor(s2, 32);
        float m1 = sm * (1.f / 128.f);
        float r1 = rsqrtf(s2 * (1.f / 128.f) - m1 * m1 + 1e-5f);

        float m1d[4], r1d[4], avd[4];
#pragma unroll
        for (int r = 0; r < 4; r++) {
            int src = quad * 4 + r;
            m1d[r] = __shfl(m1, src);
            r1d[r] = __shfl(r1, src);
            avd[r] = __shfl(avv, src);
        }

        fx4 G[8];
#pragma unroll
        for (int tile = 0; tile < 8; tile++) G[tile] = (fx4){0.f, 0.f, 0.f, 0.f};
#pragma unroll
        for (int st = 0; st < 4; st++) {
            int koff = quad * 8 + 32 * st;
#pragma unroll
            for (int tile = 0; tile < 8; tile++) {
                int n = tile * 16 + nl;
                int off = n * HH + (koff ^ (nl * 8));
                short8 bh8 = *(const short8*)(&Bhi[off]);
                short8 bl8 = *(const short8*)(&Blo[off]);
                G[tile] = __builtin_amdgcn_mfma_f32_16x16x32_bf16(Ahi[st], bh8, G[tile], 0, 0, 0);
                G[tile] = __builtin_amdgcn_mfma_f32_16x16x32_bf16(Alo[st], bh8, G[tile], 0, 0, 0);
                G[tile] = __builtin_amdgcn_mfma_f32_16x16x32_bf16(Ahi[st], bl8, G[tile], 0, 0, 0);
            }
        }

        float sm2[4] = {0.f, 0.f, 0.f, 0.f}, ss2[4] = {0.f, 0.f, 0.f, 0.f};
#pragma unroll
        for (int tile = 0; tile < 8; tile++) {
#pragma unroll
            for (int r = 0; r < 4; r++) {
                float h2 = fmaxf(r1d[r] * (G[tile][r] - m1d[r] * W1s_r[tile]) + cb_r[tile], 0.f);
                sm2[r] += h2; ss2[r] += h2 * h2;
            }
        }
#pragma unroll
        for (int r = 0; r < 4; r++) {
#pragma unroll
            for (int m = 1; m < 16; m <<= 1) {
                sm2[r] += __shfl_xor(sm2[r], m);
                ss2[r] += __shfl_xor(ss2[r], m);
            }
        }
        float mean2[4], r2v[4];
#pragma unroll
        for (int r = 0; r < 4; r++) {
            mean2[r] = sm2[r] * (1.f / 128.f);
            float var = ss2[r] * (1.f / 128.f) - mean2[r] * mean2[r];
            r2v[r] = rsqrtf(var + 1e-5f);
        }
#pragma unroll
        for (int tile = 0; tile < 8; tile++) {
#pragma unroll
            for (int r = 0; r < 4; r++) {
                float h2 = fmaxf(r1d[r] * (G[tile][r] - m1d[r] * W1s_r[tile]) + cb_r[tile], 0.f);
                float h2n = (h2 - mean2[r]) * r2v[r] * gh_r[tile] + beh_r[tile];
                if (avd[r] != 0.f) xacc[tile][r] += h2n;
            }
        }
    }

#pragma unroll
    for (int tile = 0; tile < 8; tile++)
#pragma unroll
        for (int r = 0; r < 4; r++)
            atomicAdd(&x0[(b * NN + t0 + quad * 4 + r) * HH + tile * 16 + nl], xacc[tile][r]);
}

// ---------------- K5: q,k,v,skip = x @ {Wq,Wk,Wv,Ws} + bias ----------------
__global__ void k_qkvs(const float* x, int IN,
                       const float* Wq, const float* bq,
                       const float* Wk, const float* bk,
                       const float* Wv, const float* bv,
                       const float* Ws, const float* bs,
                       float* q, float* k, float* v, float* skip) {
    __shared__ float xL[8][260];
    int r0 = blockIdx.x * 8;
    int c = threadIdx.x;
    for (int i = c; i < 8 * IN; i += 256)
        xL[i / IN][i % IN] = x[r0 * IN + i];
    __syncthreads();
    const float* Wm[4] = {Wq, Wk, Wv, Ws};
    const float* bm[4] = {bq, bk, bv, bs};
    float* om[4] = {q, k, v, skip};
    for (int m = 0; m < 4; m++) {
        const float* W = Wm[m];
        float bc = bm[m][c];
        float acc[8];
        for (int r = 0; r < 8; r++) acc[r] = bc;
        for (int kk = 0; kk < IN; kk += 4) {
            float w0 = W[(kk + 0) * HD + c];
            float w1 = W[(kk + 1) * HD + c];
            float w2 = W[(kk + 2) * HD + c];
            float w3 = W[(kk + 3) * HD + c];
            for (int r = 0; r < 8; r++) {
                acc[r] += xL[r][kk + 0] * w0 + xL[r][kk + 1] * w1
                        + xL[r][kk + 2] * w2 + xL[r][kk + 3] * w3;
            }
        }
        for (int r = 0; r < 8; r++) om[m][(r0 + r) * HD + c] = acc[r];
    }
}

// ---------------- K6: attention per (b, head, t-tile of 16) ----------------
// Block decode keeps blk%8 == b%8 so all 32 blocks sharing b land on one XCD
// (L2 reuse of K/V/Q/adjv; heuristic-only, correctness-safe).
// Coalesced adjv staging (1 line-touch each) + LDS transpose.
// Fused epilogue: xout = relu(acc + skip).
__global__ void __launch_bounds__(256) k_attn(
    const float* qb, const float* kb, const float* vb,
    const float* adjv, const float* We, const float* skip, float* xout)
{
    __shared__ float qL[16][68];      // 4.3 KB
    __shared__ float kvL[64][68];     // 17.0 KB (K then V)
    __shared__ float lg[16][132];     // 8.4 KB (logits -> alpha)
    __shared__ float ajT[16][132];    // 8.4 KB
    __shared__ float weL[DHEAD];
    __shared__ float qeL[16];
    __shared__ float bL[16];

    int blk = blockIdx.x;             // 1024
    int low3 = blk & 7;
    int m = blk >> 3;
    int b  = ((m >> 5) << 3) | low3;
    int h  = (m >> 3) & 3;
    int tt = m & 7;
    int t0 = tt * 16;
    int tid = threadIdx.x;
    int w = tid >> 6;                 // wave owns t rows [w*4, w*4+4)
    int lane = tid & 63;

    // Q: 16x64 floats as float4, coalesced
    {
        int t = tid >> 4, c4 = (tid & 15) * 4;
        *(float4*)&qL[t][c4] =
            *(const float4*)&qb[(b * NN + t0 + t) * HD + h * DHEAD + c4];
    }
    // adjv: coalesced row reads (64-B line each, touched once), LDS transpose
    for (int i = tid; i < NN * 16; i += 256) {
        int s = i >> 4, t = i & 15;
        ajT[t][s] = adjv[(b * NN + s) * NN + t0 + t];
    }
    if (tid < DHEAD) weL[tid] = We[h * DHEAD + tid];
    __syncthreads();
    if (tid < 16) {
        float z = 0.f;
        for (int d = 0; d < DHEAD; d++) z += qL[tid][d] * weL[d];
        qeL[tid] = z;
    }
    __syncthreads();

    // ---- logits in two s-halves (K staged as float4) ----
    for (int sh = 0; sh < 2; sh++) {
        for (int i = tid; i < 64 * 16; i += 256) {
            int s = i >> 4, c4 = (i & 15) * 4;
            *(float4*)&kvL[s][c4] =
                *(const float4*)&kb[(b * NN + sh * 64 + s) * HD + h * DHEAD + c4];
        }
        __syncthreads();
        for (int i = 0; i < 4; i++) {
            int t = w * 4 + i;
            float lacc = 0.f;
#pragma unroll
            for (int d4 = 0; d4 < DHEAD; d4 += 4) {
                float4 kv = *(const float4*)&kvL[lane][d4];
                float4 qv = *(const float4*)&qL[t][d4];
                lacc += kv.x * qv.x + kv.y * qv.y + kv.z * qv.z + kv.w * qv.w;
            }
            float a = ajT[t][sh * 64 + lane];
            lacc = (lacc + a * qeL[t]) * 0.125f;
            lg[t][sh * 64 + lane] = (a != 0.f) ? lacc : -1e30f;
        }
        __syncthreads();
    }

    // ---- softmax per t row (wave-private rows) ----
    for (int i = 0; i < 4; i++) {
        int t = w * 4 + i;
        float ml1 = lg[t][lane], ml2 = lg[t][lane + 64];
        float a1 = ajT[t][lane], a2 = ajT[t][lane + 64];
        float mx = fmaxf(ml1, ml2);
#pragma unroll
        for (int mm = 1; mm < 64; mm <<= 1) mx = fmaxf(mx, __shfl_xor(mx, mm));
        float e1 = (a1 != 0.f) ? __expf(ml1 - mx) : 0.f;
        float e2 = (a2 != 0.f) ? __expf(ml2 - mx) : 0.f;
        float smv = e1 + e2;
#pragma unroll
        for (int mm = 1; mm < 64; mm <<= 1) smv += __shfl_xor(smv, mm);
        float den = fmaxf(smv, 1e-16f);
        float al1 = e1 / den, al2 = e2 / den;
        float beta = al1 * a1 + al2 * a2;
#pragma unroll
        for (int mm = 1; mm < 64; mm <<= 1) beta += __shfl_xor(beta, mm);
        lg[t][lane] = al1;
        lg[t][lane + 64] = al2;
        if (lane == 0) bL[t] = beta;
    }
    __syncthreads();

    // ---- PV in two s-halves (V staged as float4); lane = d ----
    float acc[4];
#pragma unroll
    for (int i = 0; i < 4; i++) acc[i] = bL[w * 4 + i] * weL[lane];
    for (int sh = 0; sh < 2; sh++) {
        for (int i = tid; i < 64 * 16; i += 256) {
            int s = i >> 4, c4 = (i & 15) * 4;
            *(float4*)&kvL[s][c4] =
                *(const float4*)&vb[(b * NN + sh * 64 + s) * HD + h * DHEAD + c4];
        }
        __syncthreads();
        for (int s4 = 0; s4 < 64; s4 += 4) {
            float v0 = kvL[s4 + 0][lane];
            float v1 = kvL[s4 + 1][lane];
            float v2 = kvL[s4 + 2][lane];
            float v3 = kvL[s4 + 3][lane];
#pragma unroll
            for (int i = 0; i < 4; i++) {
                float4 al = *(const float4*)&lg[w * 4 + i][sh * 64 + s4];
                acc[i] += al.x * v0 + al.y * v1 + al.z * v2 + al.w * v3;
            }
        }
        __syncthreads();
    }
#pragma unroll
    for (int i = 0; i < 4; i++) {
        int gi = (b * NN + t0 + w * 4 + i) * HD + h * DHEAD + lane;
        xout[gi] = fmaxf(acc[i] + skip[gi], 0.f);
    }
}

// ---------------- K8: gather agent rows -> f32 out ----------------
__global__ void k_gather(const float* x2, const int* agent, float* out) {
    int b = blockIdx.x;
    int c = threadIdx.x;
    out[b * HD + c] = x2[(b * NN + agent[b]) * HD + c];
}

// ---------------- launch ----------------
extern "C" void kernel_launch(void* const* d_in, const int* in_sizes, int n_in,
                              void* d_out, int out_size, void* d_ws, size_t ws_size,
                              hipStream_t stream) {
    float* out = (float*)d_out;
    (void)hipGetLastError();

    bool ok = (n_in == 31) && in_sizes[0] == BB * NN * FF && in_sizes[2] == BB * NN * NN
              && in_sizes[5] == (FF + EE + 1) * HH && in_sizes[13] == HH * HD
              && in_sizes[22] == HD * HD && out_size == BB * HD;
    if (!ok) { k_sent<<<32, 256, 0, stream>>>(out, -30000.f); return; }

    const size_t WS_NEED = (size_t)8912896 * 4;
    if (ws_size < WS_NEED) { k_sent<<<32, 256, 0, stream>>>(out, -20000.f); return; }

    const float* nf    = (const float*)d_in[0];
    const int*   et    = (const int*)d_in[1];
    const float* adj   = (const float*)d_in[2];
    const int*   agent = (const int*)d_in[3];
    const float* emb   = (const float*)d_in[4];
    const float* W1    = (const float*)d_in[5];
    const float* b1    = (const float*)d_in[6];
    const float* g1    = (const float*)d_in[7];
    const float* be1   = (const float*)d_in[8];
    const float* Wh    = (const float*)d_in[9];
    const float* bh    = (const float*)d_in[10];
    const float* gh    = (const float*)d_in[11];
    const float* beh   = (const float*)d_in[12];
    const float* Wq1   = (const float*)d_in[13];
    const float* bq1   = (const float*)d_in[14];
    const float* Wk1   = (const float*)d_in[15];
    const float* bk1   = (const float*)d_in[16];
    const float* Wv1   = (const float*)d_in[17];
    const float* bv1   = (const float*)d_in[18];
    const float* We1   = (const float*)d_in[19];
    const float* Ws1   = (const float*)d_in[20];
    const float* bs1   = (const float*)d_in[21];
    const float* Wq2   = (const float*)d_in[22];
    const float* bq2   = (const float*)d_in[23];
    const float* Wk2   = (const float*)d_in[24];
    const float* bk2   = (const float*)d_in[25];
    const float* Wv2   = (const float*)d_in[26];
    const float* bv2   = (const float*)d_in[27];
    const float* We2   = (const float*)d_in[28];
    const float* Ws2   = (const float*)d_in[29];
    const float* bs2   = (const float*)d_in[30];

    float* ws   = (float*)d_ws;
    float* adjv = ws;                              // 524288
    float* base = adjv + BB * NN * NN;             // 524288
    float* x0   = base + BB * NN * HH;             // 524288
    float* q    = x0 + BB * NN * HH;               // BB*NN*HD each below
    float* k    = q + BB * NN * HD;
    float* v    = k + BB * NN * HD;
    float* skip = v + BB * NN * HD;
    float* attn = skip + BB * NN * HD;             // unused now (kept for layout)
    float* x1   = attn + BB * NN * HD;
    float* x2   = x1 + BB * NN * HD;
    (void)attn;

    // k_prep outputs live in the q region (first written AFTER econv).
    ushort_t* BhiG = (ushort_t*)q;                 // 16384 ushorts = 8192 floats
    ushort_t* BloG = BhiG + HH * HH;               // next 8192 floats
    float*    W1sW = q + 16384;                    // 128 floats
    float*    cbW  = q + 16512;                    // 128 floats

    int fail = 0;
    hipError_t e;
#define CHK(stage) do { e = hipGetLastError(); if (e != hipSuccess && fail == 0) fail = (stage); } while (0)

    k_adjv<<<BB * NN * NN / 256, 256, 0, stream>>>(adj, adjv);                       CHK(1);
    k_base<<<BB * NN, HH, 0, stream>>>(nf, et, emb, W1, b1, base);                   CHK(2);
    k_zero<<<BB * NN * HH / 256, 256, 0, stream>>>(x0);                              CHK(3);
    k_prep<<<HH, 64, 0, stream>>>(Wh, g1, be1, bh, BhiG, BloG, W1sW, cbW);           CHK(4);
    k_econv_mfma<<<512, 256, 0, stream>>>(adjv, base, W1, BhiG, BloG, W1sW, cbW,
                                          gh, beh, x0);                              CHK(5);

    k_qkvs<<<BB * NN / 8, 256, 0, stream>>>(x0, HH, Wq1, bq1, Wk1, bk1, Wv1, bv1,
                                            Ws1, bs1, q, k, v, skip);                CHK(6);
    k_attn<<<1024, 256, 0, stream>>>(q, k, v, adjv, We1, skip, x1);                  CHK(7);

    k_qkvs<<<BB * NN / 8, 256, 0, stream>>>(x1, HD, Wq2, bq2, Wk2, bk2, Wv2, bv2,
                                            Ws2, bs2, q, k, v, skip);                CHK(8);
    k_attn<<<1024, 256, 0, stream>>>(q, k, v, adjv, We2, skip, x2);                  CHK(9);

    k_gather<<<BB, HD, 0, stream>>>(x2, agent, out);                                 CHK(10);
#undef CHK

    if (fail != 0)
        k_sent<<<32, 256, 0, stream>>>(out, -(1000.f + 500.f * (float)fail));
}

// Round 9
// 476.027 us; speedup vs baseline: 3.5536x; 1.1890x over previous
//
#include <hip/hip_runtime.h>
#include <hip/hip_bf16.h>

typedef __hip_bfloat16 bf16;
typedef unsigned short ushort_t;
typedef __attribute__((ext_vector_type(8))) short short8;
typedef __attribute__((ext_vector_type(4))) float fx4;

#define BB 32
#define NN 128
#define FF 9
#define EE 8
#define HH 128
#define HD 256
#define NHEAD 4
#define DHEAD 64

__device__ __forceinline__ float us2f(ushort_t u) {
    return __uint_as_float(((unsigned int)u) << 16);
}
// truncation split: hi = trunc16(v) (round toward zero), lo = v - hi exact in f32.
__device__ __forceinline__ ushort_t f2us_tr(float f) {
    return (ushort_t)(__float_as_uint(f) >> 16);
}

__global__ void TransformerConvNet_85315230367963_kernel() {}

__global__ void k_sent(float* out, float val) {
    out[blockIdx.x * 256 + threadIdx.x] = val;
}

__global__ void k_zero(float* p) {
    p[blockIdx.x * 256 + threadIdx.x] = 0.f;
}

// ---------------- K1: adjv = adj * mask, mask = (0<adj<1) ----------------
__global__ void k_adjv(const float* adj, float* adjv) {
    int i = blockIdx.x * 256 + threadIdx.x;
    float a = adj[i];
    adjv[i] = (a > 0.f && a < 1.0f) ? a : 0.f;
}

// ---------------- K2: base[bs][c] = src(bs) @ W1[:17] + b1 ----------------
__global__ void k_base(const float* nf, const int* et, const float* emb,
                       const float* W1, const float* b1, float* base) {
    int bs = blockIdx.x;
    int c = threadIdx.x;
    int ty = et[bs];
    float acc = b1[c];
    for (int f = 0; f < FF; f++)
        acc += nf[bs * FF + f] * W1[f * HH + c];
    for (int e = 0; e < EE; e++)
        acc += emb[ty * EE + e] * W1[(FF + e) * HH + c];
    base[bs * HH + c] = acc;
}

// ---------------- K_prep: Wh' = g1*Wh split into bf16 hi/lo, swizzled ------
__global__ void k_prep(const float* Wh, const float* g1, const float* be1,
                       const float* bh, ushort_t* BhiG, ushort_t* BloG,
                       float* W1s, float* cbv) {
    int n = blockIdx.x;      // 0..127
    int t = threadIdx.x;     // 0..63
    int sw = 8 * (n & 15);
    float s1 = 0.f, s2 = 0.f;
    for (int kk = 0; kk < 2; kk++) {
        int k = t + kk * 64;
        float w = Wh[k * HH + n];
        float wp = g1[k] * w;
        ushort_t hb = f2us_tr(wp);
        float lo = wp - us2f(hb);
        BhiG[n * HH + (k ^ sw)] = hb;
        BloG[n * HH + (k ^ sw)] = f2us_tr(lo);
        s1 += wp;
        s2 += be1[k] * w;
    }
    for (int m = 1; m < 64; m <<= 1) {
        s1 += __shfl_xor(s1, m);
        s2 += __shfl_xor(s2, m);
    }
    if (t == 0) { W1s[n] = s1; cbv[n] = s2 + bh[n]; }
}

// ---------------- K_prepw: split 4 qkvs weight mats into bf16 hi/lo --------
// W[k][256] row-major; planes stored n-major with swizzle (k ^ 8*(n&15)).
__global__ void k_prepw(const float* W0, const float* W1p, const float* W2p,
                        const float* W3p, int IN, ushort_t* Whi, ushort_t* Wlo) {
    int blk = blockIdx.x;             // 4*256
    int mat = blk >> 8, n = blk & 255;
    const float* W = (mat == 0) ? W0 : (mat == 1) ? W1p : (mat == 2) ? W2p : W3p;
    ushort_t* hi = Whi + mat * 256 * IN;
    ushort_t* lo = Wlo + mat * 256 * IN;
    int sw = 8 * (n & 15);
    for (int k = threadIdx.x; k < IN; k += 64) {
        float w = W[k * HD + n];
        ushort_t hb = f2us_tr(w);
        float l = w - us2f(hb);
        hi[n * IN + (k ^ sw)] = hb;
        lo[n * IN + (k ^ sw)] = f2us_tr(l);
    }
}

// ---------------- K3: embed conv, MFMA (split-bf16 ~= f32 precision) -------
__global__ void __launch_bounds__(256) k_econv_mfma(
    const float* adjv, const float* base, const float* W1,
    const ushort_t* BhiG, const ushort_t* BloG,
    const float* W1s, const float* cbv,
    const float* ghp, const float* behp, float* x0)
{
    __shared__ __align__(16) ushort_t Bhi[HH * HH];   // 32 KB
    __shared__ __align__(16) ushort_t Blo[HH * HH];   // 32 KB

    int blk = blockIdx.x;
    int b  = blk >> 4;
    int tt = (blk >> 1) & 7;
    int sh = blk & 1;
    int t0 = tt * 16;
    int tid = threadIdx.x;
    int wv  = tid >> 6;
    int lane = tid & 63;
    int nl = lane & 15;
    int quad = lane >> 4;

    {
        const uint4* srcH = (const uint4*)BhiG;
        const uint4* srcL = (const uint4*)BloG;
        uint4* dstH = (uint4*)Bhi;
        uint4* dstL = (uint4*)Blo;
        for (int i = tid; i < HH * HH / 8; i += 256) {
            dstH[i] = srcH[i];
            dstL[i] = srcL[i];
        }
    }

    float W1s_r[8], cb_r[8], gh_r[8], beh_r[8];
#pragma unroll
    for (int tile = 0; tile < 8; tile++) {
        int c = tile * 16 + nl;
        W1s_r[tile] = W1s[c];
        cb_r[tile]  = cbv[c];
        gh_r[tile]  = ghp[c];
        beh_r[tile] = behp[c];
    }
    float w17v[4][8];
#pragma unroll
    for (int st = 0; st < 4; st++) {
        const float* p = W1 + 17 * HH + quad * 8 + 32 * st;
        float4 a = *(const float4*)p;
        float4 bq = *(const float4*)(p + 4);
        w17v[st][0] = a.x;  w17v[st][1] = a.y;  w17v[st][2] = a.z;  w17v[st][3] = a.w;
        w17v[st][4] = bq.x; w17v[st][5] = bq.y; w17v[st][6] = bq.z; w17v[st][7] = bq.w;
    }

    fx4 xacc[8];
#pragma unroll
    for (int tile = 0; tile < 8; tile++) xacc[tile] = (fx4){0.f, 0.f, 0.f, 0.f};

    __syncthreads();

    for (int i = 0; i < 16; i++) {
        int s = sh * 64 + wv * 16 + i;
        const float* brow = base + (b * NN + s) * HH;
        float avv = adjv[(b * NN + s) * NN + t0 + nl];

        // A = relu(base + avv*w17) >= 0; truncation hi/lo split (lo exact)
        short8 Ahi[4], Alo[4];
        float sm = 0.f, s2 = 0.f;
#pragma unroll
        for (int st = 0; st < 4; st++) {
            const float* p = brow + quad * 8 + 32 * st;
            float4 b0 = *(const float4*)p;
            float4 b1q = *(const float4*)(p + 4);
            float h[8] = {b0.x, b0.y, b0.z, b0.w, b1q.x, b1q.y, b1q.z, b1q.w};
            short8 ah, al;
#pragma unroll
            for (int j = 0; j < 8; j++) {
                float v = fmaxf(h[j] + avv * w17v[st][j], 0.f);
                sm += v; s2 += v * v;
                ushort_t hb = f2us_tr(v);
                float lo = v - us2f(hb);
                ah[j] = (short)hb;
                al[j] = (short)f2us_tr(lo);
            }
            Ahi[st] = ah; Alo[st] = al;
        }
        sm += __shfl_xor(sm, 16); sm += __shfl_xor(sm, 32);
        s2 += __shfl_xor(s2, 16); s2 += __shfl_xor(s2, 32);
        float m1 = sm * (1.f / 128.f);
        float r1 = rsqrtf(s2 * (1.f / 128.f) - m1 * m1 + 1e-5f);

        float m1d[4], r1d[4], avd[4];
#pragma unroll
        for (int r = 0; r < 4; r++) {
            int src = quad * 4 + r;
            m1d[r] = __shfl(m1, src);
            r1d[r] = __shfl(r1, src);
            avd[r] = __shfl(avv, src);
        }

        fx4 G[8];
#pragma unroll
        for (int tile = 0; tile < 8; tile++) G[tile] = (fx4){0.f, 0.f, 0.f, 0.f};
#pragma unroll
        for (int st = 0; st < 4; st++) {
            int koff = quad * 8 + 32 * st;
#pragma unroll
            for (int tile = 0; tile < 8; tile++) {
                int n = tile * 16 + nl;
                int off = n * HH + (koff ^ (nl * 8));
                short8 bh8 = *(const short8*)(&Bhi[off]);
                short8 bl8 = *(const short8*)(&Blo[off]);
                G[tile] = __builtin_amdgcn_mfma_f32_16x16x32_bf16(Ahi[st], bh8, G[tile], 0, 0, 0);
                G[tile] = __builtin_amdgcn_mfma_f32_16x16x32_bf16(Alo[st], bh8, G[tile], 0, 0, 0);
                G[tile] = __builtin_amdgcn_mfma_f32_16x16x32_bf16(Ahi[st], bl8, G[tile], 0, 0, 0);
            }
        }

        // h2 computed ONCE, stored back into G; LN2 stats; normalize + mask-acc
        float sm2[4] = {0.f, 0.f, 0.f, 0.f}, ss2[4] = {0.f, 0.f, 0.f, 0.f};
#pragma unroll
        for (int tile = 0; tile < 8; tile++) {
#pragma unroll
            for (int r = 0; r < 4; r++) {
                float h2 = fmaxf(r1d[r] * (G[tile][r] - m1d[r] * W1s_r[tile]) + cb_r[tile], 0.f);
                G[tile][r] = h2;
                sm2[r] += h2; ss2[r] += h2 * h2;
            }
        }
#pragma unroll
        for (int r = 0; r < 4; r++) {
#pragma unroll
            for (int m = 1; m < 16; m <<= 1) {
                sm2[r] += __shfl_xor(sm2[r], m);
                ss2[r] += __shfl_xor(ss2[r], m);
            }
        }
        float mean2[4], r2v[4];
#pragma unroll
        for (int r = 0; r < 4; r++) {
            mean2[r] = sm2[r] * (1.f / 128.f);
            float var = ss2[r] * (1.f / 128.f) - mean2[r] * mean2[r];
            r2v[r] = rsqrtf(var + 1e-5f);
        }
#pragma unroll
        for (int tile = 0; tile < 8; tile++) {
#pragma unroll
            for (int r = 0; r < 4; r++) {
                float h2n = (G[tile][r] - mean2[r]) * r2v[r] * gh_r[tile] + beh_r[tile];
                if (avd[r] != 0.f) xacc[tile][r] += h2n;
            }
        }
    }

#pragma unroll
    for (int tile = 0; tile < 8; tile++)
#pragma unroll
        for (int r = 0; r < 4; r++)
            atomicAdd(&x0[(b * NN + t0 + quad * 4 + r) * HH + tile * 16 + nl], xacc[tile][r]);
}

// ---------------- K5: qkvs via MFMA, weights from pre-split global planes --
// Grid 256 = 64 Mtiles(64 rows) x 4 Nslices(64 cols). 256 thr, wave = 16 rows.
// No LDS, no barriers: B-frags read straight from L2-resident planes.
template <int IN>
__global__ void __launch_bounds__(256) k_qkvs_mfma(
    const float* x, const ushort_t* Whi, const ushort_t* Wlo,
    const float* b0, const float* b1, const float* b2, const float* b3,
    float* o0, float* o1, float* o2, float* o3)
{
    const int ST = IN / 32;
    int blk = blockIdx.x;
    int m0 = (blk >> 2) * 64;
    int nsl = blk & 3;
    int tid = threadIdx.x;
    int wv = tid >> 6;
    int lane = tid & 63;
    int nl = lane & 15;
    int quad = lane >> 4;
    int row = m0 + wv * 16 + nl;          // A-row this lane holds

    // A-build: x[row][k], truncation hi/lo split (valid for any sign)
    short8 Ahi[ST > 0 ? ST : 1], Alo[ST > 0 ? ST : 1];
    const float* xrow = x + (long)row * IN;
#pragma unroll
    for (int st = 0; st < ST; st++) {
        const float* p = xrow + quad * 8 + 32 * st;
        float4 a = *(const float4*)p;
        float4 bq = *(const float4*)(p + 4);
        float h[8] = {a.x, a.y, a.z, a.w, bq.x, bq.y, bq.z, bq.w};
        short8 ah, al;
#pragma unroll
        for (int j = 0; j < 8; j++) {
            float v = h[j];
            ushort_t hb = f2us_tr(v);
            float lo = v - us2f(hb);
            ah[j] = (short)hb;
            al[j] = (short)f2us_tr(lo);
        }
        Ahi[st] = ah; Alo[st] = al;
    }

    const float* bs_[4] = {b0, b1, b2, b3};
    float* os_[4] = {o0, o1, o2, o3};

#pragma unroll
    for (int mat = 0; mat < 4; mat++) {
        const ushort_t* Bh = Whi + (mat * 256 + nsl * 64) * IN;
        const ushort_t* Bl = Wlo + (mat * 256 + nsl * 64) * IN;
        fx4 G[4];
#pragma unroll
        for (int tile = 0; tile < 4; tile++) {
            float bc = bs_[mat][nsl * 64 + tile * 16 + nl];
            G[tile] = (fx4){bc, bc, bc, bc};
        }
#pragma unroll
        for (int st = 0; st < ST; st++) {
            int koff = quad * 8 + 32 * st;
#pragma unroll
            for (int tile = 0; tile < 4; tile++) {
                int off = (tile * 16 + nl) * IN + (koff ^ (nl * 8));
                short8 bh8 = *(const short8*)(Bh + off);
                short8 bl8 = *(const short8*)(Bl + off);
                G[tile] = __builtin_amdgcn_mfma_f32_16x16x32_bf16(Ahi[st], bh8, G[tile], 0, 0, 0);
                G[tile] = __builtin_amdgcn_mfma_f32_16x16x32_bf16(Alo[st], bh8, G[tile], 0, 0, 0);
                G[tile] = __builtin_amdgcn_mfma_f32_16x16x32_bf16(Ahi[st], bl8, G[tile], 0, 0, 0);
            }
        }
        float* om = os_[mat];
#pragma unroll
        for (int tile = 0; tile < 4; tile++)
#pragma unroll
            for (int r = 0; r < 4; r++)
                om[(m0 + wv * 16 + quad * 4 + r) * HD + nsl * 64 + tile * 16 + nl] = G[tile][r];
    }
}

// ---------------- K6: attention per (b, head, t-tile of 16) ----------------
__global__ void __launch_bounds__(256) k_attn(
    const float* qb, const float* kb, const float* vb,
    const float* adjv, const float* We, const float* skip, float* xout)
{
    __shared__ float qL[16][68];
    __shared__ float kvL[64][68];
    __shared__ float lg[16][132];
    __shared__ float ajT[16][132];
    __shared__ float weL[DHEAD];
    __shared__ float qeL[16];
    __shared__ float bL[16];

    int blk = blockIdx.x;             // 1024
    int low3 = blk & 7;
    int m = blk >> 3;
    int b  = ((m >> 5) << 3) | low3;
    int h  = (m >> 3) & 3;
    int tt = m & 7;
    int t0 = tt * 16;
    int tid = threadIdx.x;
    int w = tid >> 6;
    int lane = tid & 63;

    {
        int t = tid >> 4, c4 = (tid & 15) * 4;
        *(float4*)&qL[t][c4] =
            *(const float4*)&qb[(b * NN + t0 + t) * HD + h * DHEAD + c4];
    }
    for (int i = tid; i < NN * 16; i += 256) {
        int s = i >> 4, t = i & 15;
        ajT[t][s] = adjv[(b * NN + s) * NN + t0 + t];
    }
    if (tid < DHEAD) weL[tid] = We[h * DHEAD + tid];
    __syncthreads();
    if (tid < 16) {
        float z = 0.f;
        for (int d = 0; d < DHEAD; d++) z += qL[tid][d] * weL[d];
        qeL[tid] = z;
    }
    __syncthreads();

    for (int sh = 0; sh < 2; sh++) {
        for (int i = tid; i < 64 * 16; i += 256) {
            int s = i >> 4, c4 = (i & 15) * 4;
            *(float4*)&kvL[s][c4] =
                *(const float4*)&kb[(b * NN + sh * 64 + s) * HD + h * DHEAD + c4];
        }
        __syncthreads();
        for (int i = 0; i < 4; i++) {
            int t = w * 4 + i;
            float lacc = 0.f;
#pragma unroll
            for (int d4 = 0; d4 < DHEAD; d4 += 4) {
                float4 kv = *(const float4*)&kvL[lane][d4];
                float4 qv = *(const float4*)&qL[t][d4];
                lacc += kv.x * qv.x + kv.y * qv.y + kv.z * qv.z + kv.w * qv.w;
            }
            float a = ajT[t][sh * 64 + lane];
            lacc = (lacc + a * qeL[t]) * 0.125f;
            lg[t][sh * 64 + lane] = (a != 0.f) ? lacc : -1e30f;
        }
        __syncthreads();
    }

    for (int i = 0; i < 4; i++) {
        int t = w * 4 + i;
        float ml1 = lg[t][lane], ml2 = lg[t][lane + 64];
        float a1 = ajT[t][lane], a2 = ajT[t][lane + 64];
        float mx = fmaxf(ml1, ml2);
#pragma unroll
        for (int mm = 1; mm < 64; mm <<= 1) mx = fmaxf(mx, __shfl_xor(mx, mm));
        float e1 = (a1 != 0.f) ? __expf(ml1 - mx) : 0.f;
        float e2 = (a2 != 0.f) ? __expf(ml2 - mx) : 0.f;
        float smv = e1 + e2;
#pragma unroll
        for (int mm = 1; mm < 64; mm <<= 1) smv += __shfl_xor(smv, mm);
        float den = fmaxf(smv, 1e-16f);
        float al1 = e1 / den, al2 = e2 / den;
        float beta = al1 * a1 + al2 * a2;
#pragma unroll
        for (int mm = 1; mm < 64; mm <<= 1) beta += __shfl_xor(beta, mm);
        lg[t][lane] = al1;
        lg[t][lane + 64] = al2;
        if (lane == 0) bL[t] = beta;
    }
    __syncthreads();

    float acc[4];
#pragma unroll
    for (int i = 0; i < 4; i++) acc[i] = bL[w * 4 + i] * weL[lane];
    for (int sh = 0; sh < 2; sh++) {
        for (int i = tid; i < 64 * 16; i += 256) {
            int s = i >> 4, c4 = (i & 15) * 4;
            *(float4*)&kvL[s][c4] =
                *(const float4*)&vb[(b * NN + sh * 64 + s) * HD + h * DHEAD + c4];
        }
        __syncthreads();
        for (int s4 = 0; s4 < 64; s4 += 4) {
            float v0 = kvL[s4 + 0][lane];
            float v1 = kvL[s4 + 1][lane];
            float v2 = kvL[s4 + 2][lane];
            float v3 = kvL[s4 + 3][lane];
#pragma unroll
            for (int i = 0; i < 4; i++) {
                float4 al = *(const float4*)&lg[w * 4 + i][sh * 64 + s4];
                acc[i] += al.x * v0 + al.y * v1 + al.z * v2 + al.w * v3;
            }
        }
        __syncthreads();
    }
#pragma unroll
    for (int i = 0; i < 4; i++) {
        int gi = (b * NN + t0 + w * 4 + i) * HD + h * DHEAD + lane;
        xout[gi] = fmaxf(acc[i] + skip[gi], 0.f);
    }
}

// ---------------- K8: gather agent rows -> f32 out ----------------
__global__ void k_gather(const float* x2, const int* agent, float* out) {
    int b = blockIdx.x;
    int c = threadIdx.x;
    out[b * HD + c] = x2[(b * NN + agent[b]) * HD + c];
}

// ---------------- launch ----------------
extern "C" void kernel_launch(void* const* d_in, const int* in_sizes, int n_in,
                              void* d_out, int out_size, void* d_ws, size_t ws_size,
                              hipStream_t stream) {
    float* out = (float*)d_out;
    (void)hipGetLastError();

    bool ok = (n_in == 31) && in_sizes[0] == BB * NN * FF && in_sizes[2] == BB * NN * NN
              && in_sizes[5] == (FF + EE + 1) * HH && in_sizes[13] == HH * HD
              && in_sizes[22] == HD * HD && out_size == BB * HD;
    if (!ok) { k_sent<<<32, 256, 0, stream>>>(out, -30000.f); return; }

    const size_t WS_NEED = (size_t)8912896 * 4;
    if (ws_size < WS_NEED) { k_sent<<<32, 256, 0, stream>>>(out, -20000.f); return; }

    const float* nf    = (const float*)d_in[0];
    const int*   et    = (const int*)d_in[1];
    const float* adj   = (const float*)d_in[2];
    const int*   agent = (const int*)d_in[3];
    const float* emb   = (const float*)d_in[4];
    const float* W1    = (const float*)d_in[5];
    const float* b1    = (const float*)d_in[6];
    const float* g1    = (const float*)d_in[7];
    const float* be1   = (const float*)d_in[8];
    const float* Wh    = (const float*)d_in[9];
    const float* bh    = (const float*)d_in[10];
    const float* gh    = (const float*)d_in[11];
    const float* beh   = (const float*)d_in[12];
    const float* Wq1   = (const float*)d_in[13];
    const float* bq1   = (const float*)d_in[14];
    const float* Wk1   = (const float*)d_in[15];
    const float* bk1   = (const float*)d_in[16];
    const float* Wv1   = (const float*)d_in[17];
    const float* bv1   = (const float*)d_in[18];
    const float* We1   = (const float*)d_in[19];
    const float* Ws1   = (const float*)d_in[20];
    const float* bs1   = (const float*)d_in[21];
    const float* Wq2   = (const float*)d_in[22];
    const float* bq2   = (const float*)d_in[23];
    const float* Wk2   = (const float*)d_in[24];
    const float* bk2   = (const float*)d_in[25];
    const float* Wv2   = (const float*)d_in[26];
    const float* bv2   = (const float*)d_in[27];
    const float* We2   = (const float*)d_in[28];
    const float* Ws2   = (const float*)d_in[29];
    const float* bs2   = (const float*)d_in[30];

    float* ws   = (float*)d_ws;
    float* adjv = ws;                              // 524288
    float* base = adjv + BB * NN * NN;             // 524288
    float* x0   = base + BB * NN * HH;             // 524288
    float* q    = x0 + BB * NN * HH;               // BB*NN*HD each below
    float* k    = q + BB * NN * HD;
    float* v    = k + BB * NN * HD;
    float* skip = v + BB * NN * HD;
    float* attn = skip + BB * NN * HD;             // region reused for weight planes
    float* x1   = attn + BB * NN * HD;
    float* x2   = x1 + BB * NN * HD;

    // econv prep planes live in q region (q first written AFTER econv).
    ushort_t* BhiG = (ushort_t*)q;                 // 16384 ushorts
    ushort_t* BloG = BhiG + HH * HH;
    float*    W1sW = q + 16384;                    // past both planes
    float*    cbW  = q + 16512;

    // qkvs weight planes live in attn region (1.5 MB of 4 MB; attn unused).
    ushort_t* WhA = (ushort_t*)attn;               // L1 hi: 4*256*128
    ushort_t* WlA = WhA + 4 * 256 * HH;            // L1 lo
    ushort_t* WhB = WlA + 4 * 256 * HH;            // L2 hi: 4*256*256
    ushort_t* WlB = WhB + 4 * 256 * HD;            // L2 lo

    int fail = 0;
    hipError_t e;
#define CHK(stage) do { e = hipGetLastError(); if (e != hipSuccess && fail == 0) fail = (stage); } while (0)

    k_adjv<<<BB * NN * NN / 256, 256, 0, stream>>>(adj, adjv);                       CHK(1);
    k_base<<<BB * NN, HH, 0, stream>>>(nf, et, emb, W1, b1, base);                   CHK(2);
    k_zero<<<BB * NN * HH / 256, 256, 0, stream>>>(x0);                              CHK(3);
    k_prep<<<HH, 64, 0, stream>>>(Wh, g1, be1, bh, BhiG, BloG, W1sW, cbW);           CHK(4);
    k_prepw<<<1024, 64, 0, stream>>>(Wq1, Wk1, Wv1, Ws1, HH, WhA, WlA);              CHK(5);
    k_prepw<<<1024, 64, 0, stream>>>(Wq2, Wk2, Wv2, Ws2, HD, WhB, WlB);              CHK(6);
    k_econv_mfma<<<512, 256, 0, stream>>>(adjv, base, W1, BhiG, BloG, W1sW, cbW,
                                          gh, beh, x0);                              CHK(7);

    k_qkvs_mfma<HH><<<256, 256, 0, stream>>>(x0, WhA, WlA, bq1, bk1, bv1, bs1,
                                             q, k, v, skip);                         CHK(8);
    k_attn<<<1024, 256, 0, stream>>>(q, k, v, adjv, We1, skip, x1);                  CHK(9);

    k_qkvs_mfma<HD><<<256, 256, 0, stream>>>(x1, WhB, WlB, bq2, bk2, bv2, bs2,
                                             q, k, v, skip);                         CHK(10);
    k_attn<<<1024, 256, 0, stream>>>(q, k, v, adjv, We2, skip, x2);                  CHK(11);

    k_gather<<<BB, HD, 0, stream>>>(x2, agent, out);                                 CHK(12);
#undef CHK

    if (fail != 0)
        k_sent<<<32, 256, 0, stream>>>(out, -(1000.f + 500.f * (float)fail));
}

// Round 10
// 363.945 us; speedup vs baseline: 4.6480x; 1.3080x over previous
//
#include <hip/hip_runtime.h>
#include <hip/hip_bf16.h>

typedef __hip_bfloat16 bf16;
typedef unsigned short ushort_t;
typedef __attribute__((ext_vector_type(8))) short short8;
typedef __attribute__((ext_vector_type(4))) float fx4;

#define BB 32
#define NN 128
#define FF 9
#define EE 8
#define HH 128
#define HD 256
#define NHEAD 4
#define DHEAD 64

__device__ __forceinline__ float us2f(ushort_t u) {
    return __uint_as_float(((unsigned int)u) << 16);
}
// truncation split: hi = trunc16(v), lo = v - hi (lo exact in f32)
__device__ __forceinline__ ushort_t f2us_tr(float f) {
    return (ushort_t)(__float_as_uint(f) >> 16);
}

__global__ void TransformerConvNet_85315230367963_kernel() {}

__global__ void k_sent(float* out, float val) {
    out[blockIdx.x * 256 + threadIdx.x] = val;
}

__global__ void k_zero(float* p) {
    p[blockIdx.x * 256 + threadIdx.x] = 0.f;
}

// ---------------- K1: adjv + adjvT (masked) ----------------
__global__ void k_adjv(const float* adj, float* adjv, float* adjvT) {
    int b = blockIdx.x;            // 32
    const float* src = adj + b * NN * NN;
    float* d1 = adjv + b * NN * NN;
    float* d2 = adjvT + b * NN * NN;
    for (int i = threadIdx.x; i < NN * NN; i += 256) {
        float a = src[i];
        d1[i] = (a > 0.f && a < 1.0f) ? a : 0.f;
    }
    for (int i = threadIdx.x; i < NN * NN; i += 256) {
        int t = i >> 7, s = i & 127;
        float a = src[s * NN + t];
        d2[i] = (a > 0.f && a < 1.0f) ? a : 0.f;   // adjvT[t][s]
    }
}

// ---------------- K2: base[bs][c] = src(bs) @ W1[:17] + b1 ----------------
__global__ void k_base(const float* nf, const int* et, const float* emb,
                       const float* W1, const float* b1, float* base) {
    int bs = blockIdx.x;
    int c = threadIdx.x;
    int ty = et[bs];
    float acc = b1[c];
    for (int f = 0; f < FF; f++)
        acc += nf[bs * FF + f] * W1[f * HH + c];
    for (int e = 0; e < EE; e++)
        acc += emb[ty * EE + e] * W1[(FF + e) * HH + c];
    base[bs * HH + c] = acc;
}

// ---------------- K_prep: Wh' = g1*Wh split bf16 hi/lo, swizzled ----------
__global__ void k_prep(const float* Wh, const float* g1, const float* be1,
                       const float* bh, ushort_t* BhiG, ushort_t* BloG,
                       float* W1s, float* cbv) {
    int n = blockIdx.x;      // 0..127
    int t = threadIdx.x;     // 0..63
    int sw = 8 * (n & 15);
    float s1 = 0.f, s2 = 0.f;
    for (int kk = 0; kk < 2; kk++) {
        int k = t + kk * 64;
        float w = Wh[k * HH + n];
        float wp = g1[k] * w;
        ushort_t hb = f2us_tr(wp);
        float lo = wp - us2f(hb);
        BhiG[n * HH + (k ^ sw)] = hb;
        BloG[n * HH + (k ^ sw)] = f2us_tr(lo);
        s1 += wp;
        s2 += be1[k] * w;
    }
    for (int m = 1; m < 64; m <<= 1) {
        s1 += __shfl_xor(s1, m);
        s2 += __shfl_xor(s2, m);
    }
    if (t == 0) { W1s[n] = s1; cbv[n] = s2 + bh[n]; }
}

// ---------------- K_prepw: split 4 qkvs weight mats into bf16 hi/lo -------
__global__ void k_prepw(const float* W0, const float* W1p, const float* W2p,
                        const float* W3p, int IN, ushort_t* Whi, ushort_t* Wlo) {
    int blk = blockIdx.x;             // 4*256
    int mat = blk >> 8, n = blk & 255;
    const float* W = (mat == 0) ? W0 : (mat == 1) ? W1p : (mat == 2) ? W2p : W3p;
    ushort_t* hi = Whi + mat * 256 * IN;
    ushort_t* lo = Wlo + mat * 256 * IN;
    int sw = 8 * (n & 15);
    for (int k = threadIdx.x; k < IN; k += 64) {
        float w = W[k * HD + n];
        ushort_t hb = f2us_tr(w);
        float l = w - us2f(hb);
        hi[n * IN + (k ^ sw)] = hb;
        lo[n * IN + (k ^ sw)] = f2us_tr(l);
    }
}

// ---------------- K3: embed conv, MFMA (split-bf16 ~= f32 precision) ------
__global__ void __launch_bounds__(256) k_econv_mfma(
    const float* adjv, const float* base, const float* W1,
    const ushort_t* BhiG, const ushort_t* BloG,
    const float* W1s, const float* cbv,
    const float* ghp, const float* behp, float* x0)
{
    __shared__ __align__(16) ushort_t Bhi[HH * HH];
    __shared__ __align__(16) ushort_t Blo[HH * HH];

    int blk = blockIdx.x;
    int b  = blk >> 4;
    int tt = (blk >> 1) & 7;
    int sh = blk & 1;
    int t0 = tt * 16;
    int tid = threadIdx.x;
    int wv  = tid >> 6;
    int lane = tid & 63;
    int nl = lane & 15;
    int quad = lane >> 4;

    {
        const uint4* srcH = (const uint4*)BhiG;
        const uint4* srcL = (const uint4*)BloG;
        uint4* dstH = (uint4*)Bhi;
        uint4* dstL = (uint4*)Blo;
        for (int i = tid; i < HH * HH / 8; i += 256) {
            dstH[i] = srcH[i];
            dstL[i] = srcL[i];
        }
    }

    float W1s_r[8], cb_r[8], gh_r[8], beh_r[8];
#pragma unroll
    for (int tile = 0; tile < 8; tile++) {
        int c = tile * 16 + nl;
        W1s_r[tile] = W1s[c];
        cb_r[tile]  = cbv[c];
        gh_r[tile]  = ghp[c];
        beh_r[tile] = behp[c];
    }
    float w17v[4][8];
#pragma unroll
    for (int st = 0; st < 4; st++) {
        const float* p = W1 + 17 * HH + quad * 8 + 32 * st;
        float4 a = *(const float4*)p;
        float4 bq = *(const float4*)(p + 4);
        w17v[st][0] = a.x;  w17v[st][1] = a.y;  w17v[st][2] = a.z;  w17v[st][3] = a.w;
        w17v[st][4] = bq.x; w17v[st][5] = bq.y; w17v[st][6] = bq.z; w17v[st][7] = bq.w;
    }

    fx4 xacc[8];
#pragma unroll
    for (int tile = 0; tile < 8; tile++) xacc[tile] = (fx4){0.f, 0.f, 0.f, 0.f};

    __syncthreads();

    for (int i = 0; i < 16; i++) {
        int s = sh * 64 + wv * 16 + i;
        const float* brow = base + (b * NN + s) * HH;
        float avv = adjv[(b * NN + s) * NN + t0 + nl];

        short8 Ahi[4], Alo[4];
        float sm = 0.f, s2 = 0.f;
#pragma unroll
        for (int st = 0; st < 4; st++) {
            const float* p = brow + quad * 8 + 32 * st;
            float4 b0 = *(const float4*)p;
            float4 b1q = *(const float4*)(p + 4);
            float h[8] = {b0.x, b0.y, b0.z, b0.w, b1q.x, b1q.y, b1q.z, b1q.w};
            short8 ah, al;
#pragma unroll
            for (int j = 0; j < 8; j++) {
                float v = fmaxf(h[j] + avv * w17v[st][j], 0.f);
                sm += v; s2 += v * v;
                ushort_t hb = f2us_tr(v);
                float lo = v - us2f(hb);
                ah[j] = (short)hb;
                al[j] = (short)f2us_tr(lo);
            }
            Ahi[st] = ah; Alo[st] = al;
        }
        sm += __shfl_xor(sm, 16); sm += __shfl_xor(sm, 32);
        s2 += __shfl_xor(s2, 16); s2 += __shfl_xor(s2, 32);
        float m1 = sm * (1.f / 128.f);
        float r1 = rsqrtf(s2 * (1.f / 128.f) - m1 * m1 + 1e-5f);

        float m1d[4], r1d[4], avd[4];
#pragma unroll
        for (int r = 0; r < 4; r++) {
            int src = quad * 4 + r;
            m1d[r] = __shfl(m1, src);
            r1d[r] = __shfl(r1, src);
            avd[r] = __shfl(avv, src);
        }

        fx4 G[8];
#pragma unroll
        for (int tile = 0; tile < 8; tile++) G[tile] = (fx4){0.f, 0.f, 0.f, 0.f};
#pragma unroll
        for (int st = 0; st < 4; st++) {
            int koff = quad * 8 + 32 * st;
#pragma unroll
            for (int tile = 0; tile < 8; tile++) {
                int n = tile * 16 + nl;
                int off = n * HH + (koff ^ (nl * 8));
                short8 bh8 = *(const short8*)(&Bhi[off]);
                short8 bl8 = *(const short8*)(&Blo[off]);
                G[tile] = __builtin_amdgcn_mfma_f32_16x16x32_bf16(Ahi[st], bh8, G[tile], 0, 0, 0);
                G[tile] = __builtin_amdgcn_mfma_f32_16x16x32_bf16(Alo[st], bh8, G[tile], 0, 0, 0);
                G[tile] = __builtin_amdgcn_mfma_f32_16x16x32_bf16(Ahi[st], bl8, G[tile], 0, 0, 0);
            }
        }

        float sm2[4] = {0.f, 0.f, 0.f, 0.f}, ss2[4] = {0.f, 0.f, 0.f, 0.f};
#pragma unroll
        for (int tile = 0; tile < 8; tile++) {
#pragma unroll
            for (int r = 0; r < 4; r++) {
                float h2 = fmaxf(r1d[r] * (G[tile][r] - m1d[r] * W1s_r[tile]) + cb_r[tile], 0.f);
                G[tile][r] = h2;
                sm2[r] += h2; ss2[r] += h2 * h2;
            }
        }
#pragma unroll
        for (int r = 0; r < 4; r++) {
#pragma unroll
            for (int m = 1; m < 16; m <<= 1) {
                sm2[r] += __shfl_xor(sm2[r], m);
                ss2[r] += __shfl_xor(ss2[r], m);
            }
        }
        float mean2[4], r2v[4];
#pragma unroll
        for (int r = 0; r < 4; r++) {
            mean2[r] = sm2[r] * (1.f / 128.f);
            float var = ss2[r] * (1.f / 128.f) - mean2[r] * mean2[r];
            r2v[r] = rsqrtf(var + 1e-5f);
        }
#pragma unroll
        for (int tile = 0; tile < 8; tile++) {
#pragma unroll
            for (int r = 0; r < 4; r++) {
                float h2n = (G[tile][r] - mean2[r]) * r2v[r] * gh_r[tile] + beh_r[tile];
                if (avd[r] != 0.f) xacc[tile][r] += h2n;
            }
        }
    }

#pragma unroll
    for (int tile = 0; tile < 8; tile++)
#pragma unroll
        for (int r = 0; r < 4; r++)
            atomicAdd(&x0[(b * NN + t0 + quad * 4 + r) * HH + tile * 16 + nl], xacc[tile][r]);
}

// ---------------- K5: qkvs via MFMA; emits q/skip f32, K planes, vT planes -
template <int IN>
__global__ void __launch_bounds__(256) k_qkvs_mfma(
    const float* x, const ushort_t* Whi, const ushort_t* Wlo,
    const float* b0, const float* b1, const float* b2, const float* b3,
    float* q, float* skipo,
    ushort_t* khi, ushort_t* klo, ushort_t* vThi, ushort_t* vTlo)
{
    const int ST = IN / 32;
    int blk = blockIdx.x;
    int m0 = (blk >> 2) * 64;
    int nsl = blk & 3;
    int tid = threadIdx.x;
    int wv = tid >> 6;
    int lane = tid & 63;
    int nl = lane & 15;
    int quad = lane >> 4;
    int row = m0 + wv * 16 + nl;

    short8 Ahi[ST], Alo[ST];
    const float* xrow = x + (long)row * IN;
#pragma unroll
    for (int st = 0; st < ST; st++) {
        const float* p = xrow + quad * 8 + 32 * st;
        float4 a = *(const float4*)p;
        float4 bq = *(const float4*)(p + 4);
        float h[8] = {a.x, a.y, a.z, a.w, bq.x, bq.y, bq.z, bq.w};
        short8 ah, al;
#pragma unroll
        for (int j = 0; j < 8; j++) {
            float v = h[j];
            ushort_t hb = f2us_tr(v);
            float lo = v - us2f(hb);
            ah[j] = (short)hb;
            al[j] = (short)f2us_tr(lo);
        }
        Ahi[st] = ah; Alo[st] = al;
    }

    const float* bs_[4] = {b0, b1, b2, b3};

#pragma unroll
    for (int mat = 0; mat < 4; mat++) {
        const ushort_t* Bh = Whi + (mat * 256 + nsl * 64) * IN;
        const ushort_t* Bl = Wlo + (mat * 256 + nsl * 64) * IN;
        fx4 G[4];
#pragma unroll
        for (int tile = 0; tile < 4; tile++) {
            float bc = bs_[mat][nsl * 64 + tile * 16 + nl];
            G[tile] = (fx4){bc, bc, bc, bc};
        }
#pragma unroll
        for (int st = 0; st < ST; st++) {
            int koff = quad * 8 + 32 * st;
#pragma unroll
            for (int tile = 0; tile < 4; tile++) {
                int off = (tile * 16 + nl) * IN + (koff ^ (nl * 8));
                short8 bh8 = *(const short8*)(Bh + off);
                short8 bl8 = *(const short8*)(Bl + off);
                G[tile] = __builtin_amdgcn_mfma_f32_16x16x32_bf16(Ahi[st], bh8, G[tile], 0, 0, 0);
                G[tile] = __builtin_amdgcn_mfma_f32_16x16x32_bf16(Alo[st], bh8, G[tile], 0, 0, 0);
                G[tile] = __builtin_amdgcn_mfma_f32_16x16x32_bf16(Ahi[st], bl8, G[tile], 0, 0, 0);
            }
        }
        int row0 = m0 + wv * 16 + quad * 4;          // rows r=0..3
        if (mat == 0 || mat == 3) {
            float* om = (mat == 0) ? q : skipo;
#pragma unroll
            for (int tile = 0; tile < 4; tile++)
#pragma unroll
                for (int r = 0; r < 4; r++)
                    om[(row0 + r) * HD + nsl * 64 + tile * 16 + nl] = G[tile][r];
        } else if (mat == 1) {
            // K planes, layout [row=b*128+s][256]
#pragma unroll
            for (int tile = 0; tile < 4; tile++) {
                int col = nsl * 64 + tile * 16 + nl;
#pragma unroll
                for (int r = 0; r < 4; r++) {
                    float gv = G[tile][r];
                    ushort_t hb = f2us_tr(gv);
                    khi[(row0 + r) * HD + col] = hb;
                    klo[(row0 + r) * HD + col] = f2us_tr(gv - us2f(hb));
                }
            }
        } else {
            // vT planes: vT[dg = b*256 + col][128 s], 4 consecutive s packed
            int bb = row0 >> 7;
            int s0 = row0 & 127;
#pragma unroll
            for (int tile = 0; tile < 4; tile++) {
                int col = nsl * 64 + tile * 16 + nl;
                int dg = bb * 256 + col;
                ushort4 h4, l4;
                float g0 = G[tile][0], g1 = G[tile][1], g2 = G[tile][2], g3 = G[tile][3];
                ushort_t h0 = f2us_tr(g0), h1 = f2us_tr(g1), h2 = f2us_tr(g2), h3 = f2us_tr(g3);
                h4.x = h0; h4.y = h1; h4.z = h2; h4.w = h3;
                l4.x = f2us_tr(g0 - us2f(h0));
                l4.y = f2us_tr(g1 - us2f(h1));
                l4.z = f2us_tr(g2 - us2f(h2));
                l4.w = f2us_tr(g3 - us2f(h3));
                *(ushort4*)&vThi[dg * NN + s0] = h4;
                *(ushort4*)&vTlo[dg * NN + s0] = l4;
            }
        }
    }
}

// ---------------- K6: attention via MFMA, 1 wave per (b,h,16-t tile) -------
__global__ void __launch_bounds__(64) k_attn_mfma(
    const float* qb, const ushort_t* khi, const ushort_t* klo,
    const ushort_t* vThi, const ushort_t* vTlo,
    const float* adjvT, const float* We, const float* skip, float* xout)
{
    __shared__ float aL[16][132];     // alpha C->A round-trip (8.4 KB)
    __shared__ float qeL[16];

    int blk = blockIdx.x;             // 1024 = 32b*4h*8tt
    int b  = blk >> 5;
    int h  = (blk >> 3) & 3;
    int tt = blk & 7;
    int t0 = tt * 16;
    int lane = threadIdx.x;
    int nl = lane & 15;
    int quad = lane >> 4;

    // ---- Q A-frags (split hi/lo) + qe partial (q . we) ----
    short8 Qhi[2], Qlo[2];
    float qe = 0.f;
#pragma unroll
    for (int ks = 0; ks < 2; ks++) {
        const float* p = qb + (b * NN + t0 + nl) * HD + h * DHEAD + quad * 8 + 32 * ks;
        const float* wp = We + h * DHEAD + quad * 8 + 32 * ks;
        float4 a0 = *(const float4*)p;
        float4 a1 = *(const float4*)(p + 4);
        float4 w0 = *(const float4*)wp;
        float4 w1 = *(const float4*)(wp + 4);
        float hv[8] = {a0.x, a0.y, a0.z, a0.w, a1.x, a1.y, a1.z, a1.w};
        float wv8[8] = {w0.x, w0.y, w0.z, w0.w, w1.x, w1.y, w1.z, w1.w};
        short8 ah, al;
#pragma unroll
        for (int j = 0; j < 8; j++) {
            float v = hv[j];
            ushort_t hb = f2us_tr(v);
            ah[j] = (short)hb;
            al[j] = (short)f2us_tr(v - us2f(hb));
            qe += v * wv8[j];
        }
        Qhi[ks] = ah; Qlo[ks] = al;
    }
    qe += __shfl_xor(qe, 16);
    qe += __shfl_xor(qe, 32);
    if (lane < 16) qeL[lane] = qe;    // qe for t = lane
    __syncthreads();
    float qe_r[4];
#pragma unroll
    for (int r = 0; r < 4; r++) qe_r[r] = qeL[quad * 4 + r];
    float we_d[4];
#pragma unroll
    for (int nt = 0; nt < 4; nt++) we_d[nt] = We[h * DHEAD + nt * 16 + nl];

    // ---- QK^T: S[t][s], 8 s-tiles ----
    fx4 S[8];
#pragma unroll
    for (int st = 0; st < 8; st++) S[st] = (fx4){0.f, 0.f, 0.f, 0.f};
#pragma unroll
    for (int ks = 0; ks < 2; ks++) {
#pragma unroll
        for (int st = 0; st < 8; st++) {
            long off = (long)(b * NN + st * 16 + nl) * HD + h * DHEAD + quad * 8 + 32 * ks;
            short8 bh8 = *(const short8*)(khi + off);
            short8 bl8 = *(const short8*)(klo + off);
            S[st] = __builtin_amdgcn_mfma_f32_16x16x32_bf16(Qhi[ks], bh8, S[st], 0, 0, 0);
            S[st] = __builtin_amdgcn_mfma_f32_16x16x32_bf16(Qlo[ks], bh8, S[st], 0, 0, 0);
            S[st] = __builtin_amdgcn_mfma_f32_16x16x32_bf16(Qhi[ks], bl8, S[st], 0, 0, 0);
        }
    }

    // ---- masked logits (D-layout: row t = quad*4+r, col s = st*16+nl) ----
    float av[8][4];
#pragma unroll
    for (int st = 0; st < 8; st++)
#pragma unroll
        for (int r = 0; r < 4; r++)
            av[st][r] = adjvT[(b * NN + t0 + quad * 4 + r) * NN + st * 16 + nl];
#pragma unroll
    for (int st = 0; st < 8; st++)
#pragma unroll
        for (int r = 0; r < 4; r++) {
            float a = av[st][r];
            S[st][r] = (a != 0.f) ? (S[st][r] + a * qe_r[r]) * 0.125f : -1e30f;
        }

    // ---- softmax per row: reduce over s = in-lane stiles + xor{1,2,4,8} ----
    float mx[4], den[4], beta[4];
#pragma unroll
    for (int r = 0; r < 4; r++) {
        float m = S[0][r];
#pragma unroll
        for (int st = 1; st < 8; st++) m = fmaxf(m, S[st][r]);
#pragma unroll
        for (int mm = 1; mm < 16; mm <<= 1) m = fmaxf(m, __shfl_xor(m, mm));
        mx[r] = m;
    }
#pragma unroll
    for (int r = 0; r < 4; r++) den[r] = 0.f;
#pragma unroll
    for (int st = 0; st < 8; st++)
#pragma unroll
        for (int r = 0; r < 4; r++) {
            float e = (av[st][r] != 0.f) ? __expf(S[st][r] - mx[r]) : 0.f;
            S[st][r] = e;
            den[r] += e;
        }
#pragma unroll
    for (int r = 0; r < 4; r++) {
#pragma unroll
        for (int mm = 1; mm < 16; mm <<= 1) den[r] += __shfl_xor(den[r], mm);
        den[r] = 1.f / fmaxf(den[r], 1e-16f);
        beta[r] = 0.f;
    }
#pragma unroll
    for (int st = 0; st < 8; st++)
#pragma unroll
        for (int r = 0; r < 4; r++) {
            float al = S[st][r] * den[r];
            S[st][r] = al;
            beta[r] += al * av[st][r];
        }
#pragma unroll
    for (int r = 0; r < 4; r++)
#pragma unroll
        for (int mm = 1; mm < 16; mm <<= 1) beta[r] += __shfl_xor(beta[r], mm);

    // ---- alpha C-layout -> LDS -> A-layout frags (hi only) ----
#pragma unroll
    for (int st = 0; st < 8; st++)
#pragma unroll
        for (int r = 0; r < 4; r++)
            aL[quad * 4 + r][st * 16 + nl] = S[st][r];
    __syncthreads();
    short8 Ah[4];
#pragma unroll
    for (int ks = 0; ks < 4; ks++) {
        const float* p = &aL[nl][quad * 8 + 32 * ks];
        float4 a0 = *(const float4*)p;
        float4 a1 = *(const float4*)(p + 4);
        float hv[8] = {a0.x, a0.y, a0.z, a0.w, a1.x, a1.y, a1.z, a1.w};
        short8 ah;
#pragma unroll
        for (int j = 0; j < 8; j++) ah[j] = (short)f2us_tr(hv[j]);
        Ah[ks] = ah;
    }

    // ---- PV: out[t][d] = beta*we + alpha @ V (V via vT planes) ----
    fx4 G[4];
#pragma unroll
    for (int nt = 0; nt < 4; nt++) {
        fx4 g;
#pragma unroll
        for (int r = 0; r < 4; r++) g[r] = beta[r] * we_d[nt];
        G[nt] = g;
    }
#pragma unroll
    for (int ks = 0; ks < 4; ks++) {
#pragma unroll
        for (int nt = 0; nt < 4; nt++) {
            long dg = (long)(b * 256 + h * DHEAD + nt * 16 + nl);
            const short8 vh = *(const short8*)(vThi + dg * NN + quad * 8 + 32 * ks);
            const short8 vl = *(const short8*)(vTlo + dg * NN + quad * 8 + 32 * ks);
            G[nt] = __builtin_amdgcn_mfma_f32_16x16x32_bf16(Ah[ks], vh, G[nt], 0, 0, 0);
            G[nt] = __builtin_amdgcn_mfma_f32_16x16x32_bf16(Ah[ks], vl, G[nt], 0, 0, 0);
        }
    }

    // ---- epilogue: relu(out + skip) ----
#pragma unroll
    for (int nt = 0; nt < 4; nt++)
#pragma unroll
        for (int r = 0; r < 4; r++) {
            int gi = (b * NN + t0 + quad * 4 + r) * HD + h * DHEAD + nt * 16 + nl;
            xout[gi] = fmaxf(G[nt][r] + skip[gi], 0.f);
        }
}

// ---------------- K8: gather agent rows -> f32 out ----------------
__global__ void k_gather(const float* x2, const int* agent, float* out) {
    int b = blockIdx.x;
    int c = threadIdx.x;
    out[b * HD + c] = x2[(b * NN + agent[b]) * HD + c];
}

// ---------------- launch ----------------
extern "C" void kernel_launch(void* const* d_in, const int* in_sizes, int n_in,
                              void* d_out, int out_size, void* d_ws, size_t ws_size,
                              hipStream_t stream) {
    float* out = (float*)d_out;
    (void)hipGetLastError();

    bool ok = (n_in == 31) && in_sizes[0] == BB * NN * FF && in_sizes[2] == BB * NN * NN
              && in_sizes[5] == (FF + EE + 1) * HH && in_sizes[13] == HH * HD
              && in_sizes[22] == HD * HD && out_size == BB * HD;
    if (!ok) { k_sent<<<32, 256, 0, stream>>>(out, -30000.f); return; }

    const size_t WS_NEED = (size_t)8912896 * 4;
    if (ws_size < WS_NEED) { k_sent<<<32, 256, 0, stream>>>(out, -20000.f); return; }

    const float* nf    = (const float*)d_in[0];
    const int*   et    = (const int*)d_in[1];
    const float* adj   = (const float*)d_in[2];
    const int*   agent = (const int*)d_in[3];
    const float* emb   = (const float*)d_in[4];
    const float* W1    = (const float*)d_in[5];
    const float* b1    = (const float*)d_in[6];
    const float* g1    = (const float*)d_in[7];
    const float* be1   = (const float*)d_in[8];
    const float* Wh    = (const float*)d_in[9];
    const float* bh    = (const float*)d_in[10];
    const float* gh    = (const float*)d_in[11];
    const float* beh   = (const float*)d_in[12];
    const float* Wq1   = (const float*)d_in[13];
    const float* bq1   = (const float*)d_in[14];
    const float* Wk1   = (const float*)d_in[15];
    const float* bk1   = (const float*)d_in[16];
    const float* Wv1   = (const float*)d_in[17];
    const float* bv1   = (const float*)d_in[18];
    const float* We1   = (const float*)d_in[19];
    const float* Ws1   = (const float*)d_in[20];
    const float* bs1   = (const float*)d_in[21];
    const float* Wq2   = (const float*)d_in[22];
    const float* bq2   = (const float*)d_in[23];
    const float* Wk2   = (const float*)d_in[24];
    const float* bk2   = (const float*)d_in[25];
    const float* Wv2   = (const float*)d_in[26];
    const float* bv2   = (const float*)d_in[27];
    const float* We2   = (const float*)d_in[28];
    const float* Ws2   = (const float*)d_in[29];
    const float* bs2   = (const float*)d_in[30];

    float* ws   = (float*)d_ws;
    float* adjv = ws;                              // 524288 f
    float* base = adjv + BB * NN * NN;             // 524288 f
    float* x0   = base + BB * NN * HH;             // 524288 f
    float* q    = x0 + BB * NN * HH;               // 1048576 f
    float* kreg = q + BB * NN * HD;                // 1048576 f -> khi/klo
    float* vreg = kreg + BB * NN * HD;             // 1048576 f -> vThi/vTlo
    float* skip = vreg + BB * NN * HD;             // 1048576 f
    float* areg = skip + BB * NN * HD;             // 1048576 f -> weight planes + adjvT
    float* x1   = areg + BB * NN * HD;
    float* x2   = x1 + BB * NN * HD;

    // econv prep planes in q region (q first written AFTER econv)
    ushort_t* BhiG = (ushort_t*)q;
    ushort_t* BloG = BhiG + HH * HH;
    float*    W1sW = q + 16384;
    float*    cbW  = q + 16512;

    // K / vT planes
    ushort_t* khi  = (ushort_t*)kreg;              // 1048576 ush
    ushort_t* klo  = khi + BB * NN * HD;           // 1048576 ush
    ushort_t* vThi = (ushort_t*)vreg;
    ushort_t* vTlo = vThi + BB * NN * HD;

    // qkvs weight planes + adjvT in areg (4 MB): 1.5 MB planes + 2 MB adjvT
    ushort_t* WhA = (ushort_t*)areg;               // 4*256*128 ush
    ushort_t* WlA = WhA + 4 * 256 * HH;
    ushort_t* WhB = WlA + 4 * 256 * HH;            // 4*256*256 ush
    ushort_t* WlB = WhB + 4 * 256 * HD;
    float* adjvT  = areg + 393216;                 // 524288 f, past planes

    int fail = 0;
    hipError_t e;
#define CHK(stage) do { e = hipGetLastError(); if (e != hipSuccess && fail == 0) fail = (stage); } while (0)

    k_adjv<<<BB, 256, 0, stream>>>(adj, adjv, adjvT);                                CHK(1);
    k_base<<<BB * NN, HH, 0, stream>>>(nf, et, emb, W1, b1, base);                   CHK(2);
    k_zero<<<BB * NN * HH / 256, 256, 0, stream>>>(x0);                              CHK(3);
    k_prep<<<HH, 64, 0, stream>>>(Wh, g1, be1, bh, BhiG, BloG, W1sW, cbW);           CHK(4);
    k_prepw<<<1024, 64, 0, stream>>>(Wq1, Wk1, Wv1, Ws1, HH, WhA, WlA);              CHK(5);
    k_prepw<<<1024, 64, 0, stream>>>(Wq2, Wk2, Wv2, Ws2, HD, WhB, WlB);              CHK(6);
    k_econv_mfma<<<512, 256, 0, stream>>>(adjv, base, W1, BhiG, BloG, W1sW, cbW,
                                          gh, beh, x0);                              CHK(7);

    k_qkvs_mfma<HH><<<256, 256, 0, stream>>>(x0, WhA, WlA, bq1, bk1, bv1, bs1,
                                             q, skip, khi, klo, vThi, vTlo);         CHK(8);
    k_attn_mfma<<<1024, 64, 0, stream>>>(q, khi, klo, vThi, vTlo, adjvT, We1,
                                         skip, x1);                                  CHK(9);

    k_qkvs_mfma<HD><<<256, 256, 0, stream>>>(x1, WhB, WlB, bq2, bk2, bv2, bs2,
                                             q, skip, khi, klo, vThi, vTlo);         CHK(10);
    k_attn_mfma<<<1024, 64, 0, stream>>>(q, khi, klo, vThi, vTlo, adjvT, We2,
                                         skip, x2);                                  CHK(11);

    k_gather<<<BB, HD, 0, stream>>>(x2, agent, out);                                 CHK(12);
#undef CHK

    if (fail != 0)
        k_sent<<<32, 256, 0, stream>>>(out, -(1000.f + 500.f * (float)fail));
}